// Round 9
// baseline (235.329 us; speedup 1.0000x reference)
//
#include <hip/hip_runtime.h>
#include <hip/hip_fp16.h>
#include <math.h>

#define NEG_SLOPE 0.2f

typedef _Float16 f16x8 __attribute__((ext_vector_type(8)));
typedef float    f32x4 __attribute__((ext_vector_type(4)));

__device__ __forceinline__ void get_edge(const int* __restrict__ ei, int E, int e,
                                         int& s, int& d) {
    if (e < E) { s = ei[e]; d = ei[E + e]; }
    else       { s = e - E; d = e - E; }
}

// ================= CSR build: bucket two-pass, no device-scope random atomics ==========
__global__ void zero_bcnt(int* __restrict__ bcnt, int nbuck) {
    if (threadIdx.x < nbuck) bcnt[threadIdx.x] = 0;
}

__global__ __launch_bounds__(256) void bucket_count(const int* __restrict__ ei, int E, int ET,
                                                    int* __restrict__ bcnt) {
    __shared__ int lhist[256];
    int t = threadIdx.x;
    lhist[t] = 0;
    __syncthreads();
    int start = blockIdx.x * 4096;
#pragma unroll
    for (int k = 0; k < 16; ++k) {
        int e = start + t + k * 256;
        if (e < ET) { int s, d; get_edge(ei, E, e, s, d); atomicAdd(&lhist[d >> 8], 1); }
    }
    __syncthreads();
    if (lhist[t] > 0) atomicAdd(&bcnt[t], lhist[t]);
}

__global__ void bucket_scan(const int* __restrict__ bcnt, int* __restrict__ bbase,
                            int* __restrict__ bcur, int* __restrict__ row_ptr,
                            int nbuck, int N, int ET) {
    __shared__ int buf[256];
    int t = threadIdx.x;
    int v = (t < nbuck) ? bcnt[t] : 0;
    buf[t] = v;
    __syncthreads();
    for (int off = 1; off < 256; off <<= 1) {
        int u = (t >= off) ? buf[t - off] : 0;
        __syncthreads();
        buf[t] += u;
        __syncthreads();
    }
    if (t < nbuck) { int ex = buf[t] - v; bbase[t] = ex; bcur[t] = ex; }
    if (t == 0) row_ptr[N] = ET;
}

__global__ __launch_bounds__(256) void bucket_scatter(const int* __restrict__ ei, int E, int ET,
                                                      int* __restrict__ bcur,
                                                      unsigned int* __restrict__ bstore,
                                                      int nbuck) {
    __shared__ int lhist[256], lbase[256], lrank[256], gbase[256];
    __shared__ unsigned int sbuf[4096];
    __shared__ int saddr[4096];
    int t = threadIdx.x;
    int start = blockIdx.x * 4096;
    int cnt = ET - start; if (cnt > 4096) cnt = 4096;
    lhist[t] = 0; lrank[t] = 0;
    __syncthreads();
    int mybuck[16]; unsigned int myval[16];
#pragma unroll
    for (int k = 0; k < 16; ++k) {
        int e = start + t + k * 256;
        mybuck[k] = -1;
        if (e < ET) {
            int s, d; get_edge(ei, E, e, s, d);
            mybuck[k] = d >> 8;
            myval[k] = ((unsigned int)d << 16) | (unsigned int)s;
            atomicAdd(&lhist[mybuck[k]], 1);
        }
    }
    __syncthreads();
    int v = lhist[t];
    lbase[t] = v;
    __syncthreads();
    for (int off = 1; off < 256; off <<= 1) {
        int u = (t >= off) ? lbase[t - off] : 0;
        __syncthreads();
        lbase[t] += u;
        __syncthreads();
    }
    int excl = lbase[t] - v;
    if (t < nbuck && v > 0) gbase[t] = atomicAdd(&bcur[t], v);
    __syncthreads();
    lbase[t] = excl;
    __syncthreads();
#pragma unroll
    for (int k = 0; k < 16; ++k) {
        int b = mybuck[k];
        if (b >= 0) {
            int r = atomicAdd(&lrank[b], 1);
            int idx = lbase[b] + r;
            sbuf[idx] = myval[k];
            saddr[idx] = gbase[b] + r;
        }
    }
    __syncthreads();
    for (int j = t; j < cnt; j += 256)
        bstore[saddr[j]] = sbuf[j];
}

__global__ __launch_bounds__(256) void bucket_csr(const unsigned int* __restrict__ bstore,
                                                  const int* __restrict__ bcnt,
                                                  const int* __restrict__ bbase,
                                                  int* __restrict__ row_ptr,
                                                  int* __restrict__ col, int N) {
    __shared__ int lcnt[256], lexcl[256], lrank[256];
    int b = blockIdx.x, t = threadIdx.x;
    int nb = bcnt[b], base = bbase[b];
    lcnt[t] = 0; lrank[t] = 0;
    __syncthreads();
    for (int i = t; i < nb; i += 256)
        atomicAdd(&lcnt[(bstore[base + i] >> 16) & 255], 1);
    __syncthreads();
    int v = lcnt[t];
    lexcl[t] = v;
    __syncthreads();
    for (int off = 1; off < 256; off <<= 1) {
        int u = (t >= off) ? lexcl[t - off] : 0;
        __syncthreads();
        lexcl[t] += u;
        __syncthreads();
    }
    int ex = lexcl[t] - v;
    __syncthreads();
    lexcl[t] = ex;
    __syncthreads();
    int node = (b << 8) + t;
    if (node < N) row_ptr[node] = base + ex;
    for (int i = t; i < nb; i += 256) {
        unsigned int pk = bstore[base + i];
        int d8 = (pk >> 16) & 255;
        int r = atomicAdd(&lrank[d8], 1);
        col[base + lexcl[d8] + r] = (int)(pk & 0xFFFFu);
    }
}

// ========== GEMM1 (MFMA f16): h1[N,64](f16) = x[N,128] @ W1[128,64] + att1 ==========
__global__ __launch_bounds__(256) void gemm1_kernel(const float* __restrict__ x,
                                                    const float* __restrict__ W,
                                                    const float* __restrict__ asrc,
                                                    const float* __restrict__ adst,
                                                    _Float16* __restrict__ hout,
                                                    float* __restrict__ av,
                                                    float* __restrict__ bv, int N) {
    __shared__ unsigned int sWu[4096];  // 16 frags * 64 lanes * 4 uints (16 KB)
    for (int p = threadIdx.x; p < 4096; p += 256) {
        int frag = p >> 8;
        int lane = (p >> 2) & 63;
        int j2   = p & 3;
        int chunk = frag >> 2, nt = frag & 3;
        int k = chunk * 32 + ((lane >> 4) << 3) + (j2 << 1);
        int n = nt * 16 + (lane & 15);
        union { _Float16 h[2]; unsigned int u; } pk;
        pk.h[0] = (_Float16)W[k * 64 + n];
        pk.h[1] = (_Float16)W[(k + 1) * 64 + n];
        sWu[p] = pk.u;
    }
    __syncthreads();

    int lane = threadIdx.x & 63;
    int wid  = threadIdx.x >> 6;
    int rbase = blockIdx.x * 64 + wid * 16;
    int l15 = lane & 15, quad = lane >> 4;
    int rA = rbase + l15; if (rA >= N) rA = N - 1;

    const unsigned int* fragbase = &sWu[lane * 4];
    f32x4 z = {0.f, 0.f, 0.f, 0.f};
    f32x4 acc[4] = {z, z, z, z};

#pragma unroll
    for (int chunk = 0; chunk < 4; ++chunk) {
        const float* xp = x + (size_t)rA * 128 + chunk * 32 + quad * 8;
        float4 f0 = *((const float4*)xp);
        float4 f1 = *((const float4*)(xp + 4));
        f16x8 af;
        af[0] = (_Float16)f0.x; af[1] = (_Float16)f0.y;
        af[2] = (_Float16)f0.z; af[3] = (_Float16)f0.w;
        af[4] = (_Float16)f1.x; af[5] = (_Float16)f1.y;
        af[6] = (_Float16)f1.z; af[7] = (_Float16)f1.w;
#pragma unroll
        for (int t = 0; t < 4; ++t) {
            f16x8 bf = *((const f16x8*)(fragbase + (chunk * 4 + t) * 256));
            acc[t] = __builtin_amdgcn_mfma_f32_16x16x32_f16(af, bf, acc[t], 0, 0, 0);
        }
    }

    float asc[4], adc[4];
#pragma unroll
    for (int t = 0; t < 4; ++t) { asc[t] = asrc[t * 16 + l15]; adc[t] = adst[t * 16 + l15]; }
#pragma unroll
    for (int reg = 0; reg < 4; ++reg) {
        int r = rbase + quad * 4 + reg;
        bool ok = (r < N);
#pragma unroll
        for (int t = 0; t < 4; ++t) {
            float v = acc[t][reg];
            if (ok) hout[(size_t)r * 64 + t * 16 + l15] = (_Float16)v;
            float pa = v * asc[t], pb = v * adc[t];
            pa += __shfl_xor(pa, 1); pb += __shfl_xor(pb, 1);
            pa += __shfl_xor(pa, 2); pb += __shfl_xor(pb, 2);
            pa += __shfl_xor(pa, 4); pb += __shfl_xor(pb, 4);
            if (ok && (lane & 7) == 0) {
                int head = t * 2 + (l15 >> 3);
                av[r * 8 + head] = pa;
                bv[r * 8 + head] = pb;
            }
        }
    }
}

// ========== fused layer-1 softmax-aggregate ==========
// Wave = 1 node; 16 groups of 4 lanes own edges e = beg+g, step 16.
// Lane (gl) covers halfs 16gl..16gl+15 (32 B of the 128-B row) = heads 2gl, 2gl+1.
// Depth-2 pipeline -> ~16 row-gathers in flight per wave; per-head sums s0,s1.
__global__ __launch_bounds__(256) void agg1_kernel(const int* __restrict__ rp,
                                                   const int* __restrict__ col,
                                                   const float* __restrict__ av,
                                                   const float* __restrict__ bv,
                                                   const __half* __restrict__ h1,
                                                   const float* __restrict__ b1,
                                                   float* __restrict__ out1, int N) {
    int node = blockIdx.x * 4 + (threadIdx.x >> 6);
    int lane = threadIdx.x & 63;
    if (node >= N) return;
    int g = lane >> 2, gl = lane & 3;
    int beg = rp[node], end = rp[node + 1];
    int last = end - 1;
    float2 bd2 = ((const float2*)bv)[node * 4 + gl];
    const uint4* hrow = (const uint4*)h1;     // 8 uint4 per row
    const float2* av2 = (const float2*)av;

    uint4 z4 = {0u, 0u, 0u, 0u};
    int e  = beg + g;
    int c  = col[e <= last ? e : last];
    int e2 = e + 16;
    int cn = col[e2 <= last ? e2 : last];
    float2 avc = make_float2(0.f, 0.f);
    uint4 hc0 = z4, hc1 = z4;
    if (e < end) {
        avc = av2[(size_t)c * 4 + gl];
        hc0 = hrow[(size_t)c * 8 + gl * 2];
        hc1 = hrow[(size_t)c * 8 + gl * 2 + 1];
    }

    float s0 = 0.f, s1 = 0.f, a[16];
#pragma unroll
    for (int i = 0; i < 16; ++i) a[i] = 0.f;
    for (; e < end; e += 16) {
        int en = e + 16;
        float2 avn = make_float2(0.f, 0.f);
        uint4 hn0 = z4, hn1 = z4;
        if (en < end) {
            avn = av2[(size_t)cn * 4 + gl];
            hn0 = hrow[(size_t)cn * 8 + gl * 2];
            hn1 = hrow[(size_t)cn * 8 + gl * 2 + 1];
        }
        int ef = en + 16;
        int cf = col[ef <= last ? ef : last];
        float l0 = avc.x + bd2.x; l0 = l0 > 0.f ? l0 : NEG_SLOPE * l0;
        float l1 = avc.y + bd2.y; l1 = l1 > 0.f ? l1 : NEG_SLOPE * l1;
        float w0 = __expf(l0), w1 = __expf(l1);
        s0 += w0; s1 += w1;
        const __half2* hp0 = (const __half2*)&hc0;
        const __half2* hp1 = (const __half2*)&hc1;
#pragma unroll
        for (int i = 0; i < 4; ++i) {
            float2 f = __half22float2(hp0[i]);
            a[2 * i]     = fmaf(w0, f.x, a[2 * i]);
            a[2 * i + 1] = fmaf(w0, f.y, a[2 * i + 1]);
        }
#pragma unroll
        for (int i = 0; i < 4; ++i) {
            float2 f = __half22float2(hp1[i]);
            a[8 + 2 * i]     = fmaf(w1, f.x, a[8 + 2 * i]);
            a[8 + 2 * i + 1] = fmaf(w1, f.y, a[8 + 2 * i + 1]);
        }
        avc = avn; hc0 = hn0; hc1 = hn1; cn = cf;
    }
#pragma unroll
    for (int off = 4; off < 64; off <<= 1) {
        s0 += __shfl_xor(s0, off);
        s1 += __shfl_xor(s1, off);
#pragma unroll
        for (int i = 0; i < 16; ++i) a[i] += __shfl_xor(a[i], off);
    }
    if (g == 0) {
        float inv0 = 1.0f / s0, inv1 = 1.0f / s1;
#pragma unroll
        for (int q = 0; q < 4; ++q) {
            float inv = (q < 2) ? inv0 : inv1;
            float4 bb = ((const float4*)b1)[gl * 4 + q];
            float v0 = a[4 * q]     * inv + bb.x;
            float v1 = a[4 * q + 1] * inv + bb.y;
            float v2 = a[4 * q + 2] * inv + bb.z;
            float v3 = a[4 * q + 3] * inv + bb.w;
            v0 = v0 > 0.f ? v0 : expm1f(v0);
            v1 = v1 > 0.f ? v1 : expm1f(v1);
            v2 = v2 > 0.f ? v2 : expm1f(v2);
            v3 = v3 > 0.f ? v3 : expm1f(v3);
            ((float4*)out1)[(size_t)node * 16 + gl * 4 + q] = make_float4(v0, v1, v2, v3);
        }
    }
}

// ========== GEMM2 (MFMA f16): h2[N,128](f16) = out1[N,64] @ W2[64,128] + att2 ==========
__global__ __launch_bounds__(256) void gemm2_kernel(const float* __restrict__ he,
                                                    const float* __restrict__ W,
                                                    const float* __restrict__ asrc,
                                                    const float* __restrict__ adst,
                                                    _Float16* __restrict__ h2,
                                                    float* __restrict__ av,
                                                    float* __restrict__ bv, int N) {
    __shared__ unsigned int sWu[4096];  // 16 frags (16 KB)
    for (int p = threadIdx.x; p < 4096; p += 256) {
        int frag = p >> 8;
        int lane = (p >> 2) & 63;
        int j2   = p & 3;
        int chunk = frag >> 3, nt = frag & 7;
        int k = chunk * 32 + ((lane >> 4) << 3) + (j2 << 1);
        int n = nt * 16 + (lane & 15);
        union { _Float16 h[2]; unsigned int u; } pk;
        pk.h[0] = (_Float16)W[k * 128 + n];
        pk.h[1] = (_Float16)W[(k + 1) * 128 + n];
        sWu[p] = pk.u;
    }
    __syncthreads();

    int lane = threadIdx.x & 63;
    int wid  = threadIdx.x >> 6;
    int rbase = blockIdx.x * 64 + wid * 16;
    int l15 = lane & 15, quad = lane >> 4;
    int rA = rbase + l15; if (rA >= N) rA = N - 1;

    const unsigned int* fragbase = &sWu[lane * 4];
    f32x4 z = {0.f, 0.f, 0.f, 0.f};
    f32x4 acc[8] = {z, z, z, z, z, z, z, z};

#pragma unroll
    for (int chunk = 0; chunk < 2; ++chunk) {
        const float* xp = he + (size_t)rA * 64 + chunk * 32 + quad * 8;
        float4 f0 = *((const float4*)xp);
        float4 f1 = *((const float4*)(xp + 4));
        f16x8 af;
        af[0] = (_Float16)f0.x; af[1] = (_Float16)f0.y;
        af[2] = (_Float16)f0.z; af[3] = (_Float16)f0.w;
        af[4] = (_Float16)f1.x; af[5] = (_Float16)f1.y;
        af[6] = (_Float16)f1.z; af[7] = (_Float16)f1.w;
#pragma unroll
        for (int t = 0; t < 8; ++t) {
            f16x8 bf = *((const f16x8*)(fragbase + (chunk * 8 + t) * 256));
            acc[t] = __builtin_amdgcn_mfma_f32_16x16x32_f16(af, bf, acc[t], 0, 0, 0);
        }
    }

    float asc[8], adc[8];
#pragma unroll
    for (int t = 0; t < 8; ++t) { asc[t] = asrc[t * 16 + l15]; adc[t] = adst[t * 16 + l15]; }
#pragma unroll
    for (int reg = 0; reg < 4; ++reg) {
        int r = rbase + quad * 4 + reg;
        bool ok = (r < N);
        float pa = 0.0f, pb = 0.0f;
#pragma unroll
        for (int t = 0; t < 8; ++t) {
            float v = acc[t][reg];
            if (ok) h2[(size_t)r * 128 + t * 16 + l15] = (_Float16)v;
            pa = fmaf(v, asc[t], pa);
            pb = fmaf(v, adc[t], pb);
        }
        pa += __shfl_xor(pa, 1); pb += __shfl_xor(pb, 1);
        pa += __shfl_xor(pa, 2); pb += __shfl_xor(pb, 2);
        pa += __shfl_xor(pa, 4); pb += __shfl_xor(pb, 4);
        pa += __shfl_xor(pa, 8); pb += __shfl_xor(pb, 8);
        if (ok && l15 == 0) { av[r] = pa; bv[r] = pb; }
    }
}

// ========== fused layer-2 softmax-aggregate ==========
// Wave = 1 node; 8 groups of 8 lanes own edges e = beg+g, step 8.
// Lane (gl) covers halfs 16gl..16gl+15 (32 B of the 256-B row).
// Depth-2 pipeline -> ~16 row-gathers in flight per wave.
__global__ __launch_bounds__(256) void agg2_kernel(const int* __restrict__ rp,
                                                   const int* __restrict__ col,
                                                   const float* __restrict__ av,
                                                   const float* __restrict__ bv,
                                                   const __half* __restrict__ h2,
                                                   const float* __restrict__ b2,
                                                   float* __restrict__ dout, int N) {
    int node = blockIdx.x * 4 + (threadIdx.x >> 6);
    int lane = threadIdx.x & 63;
    if (node >= N) return;
    int g = lane >> 3, gl = lane & 7;
    int beg = rp[node], end = rp[node + 1];
    int last = end - 1;
    float bd = bv[node];
    const uint4* hrow = (const uint4*)h2;     // 16 uint4 per row

    uint4 z4 = {0u, 0u, 0u, 0u};
    int e  = beg + g;
    int c  = col[e <= last ? e : last];
    int e2 = e + 8;
    int cn = col[e2 <= last ? e2 : last];
    float avc = 0.f;
    uint4 hc0 = z4, hc1 = z4;
    if (e < end) {
        avc = av[c];
        hc0 = hrow[(size_t)c * 16 + gl * 2];
        hc1 = hrow[(size_t)c * 16 + gl * 2 + 1];
    }

    float s = 0.f, a[16];
#pragma unroll
    for (int i = 0; i < 16; ++i) a[i] = 0.f;
    for (; e < end; e += 8) {
        int en = e + 8;
        float avn = 0.f;
        uint4 hn0 = z4, hn1 = z4;
        if (en < end) {
            avn = av[cn];
            hn0 = hrow[(size_t)cn * 16 + gl * 2];
            hn1 = hrow[(size_t)cn * 16 + gl * 2 + 1];
        }
        int ef = en + 8;
        int cf = col[ef <= last ? ef : last];
        float l = avc + bd;
        l = l > 0.f ? l : NEG_SLOPE * l;
        float w = __expf(l);
        s += w;
        const __half2* hp0 = (const __half2*)&hc0;
        const __half2* hp1 = (const __half2*)&hc1;
#pragma unroll
        for (int i = 0; i < 4; ++i) {
            float2 f = __half22float2(hp0[i]);
            a[2 * i]     = fmaf(w, f.x, a[2 * i]);
            a[2 * i + 1] = fmaf(w, f.y, a[2 * i + 1]);
        }
#pragma unroll
        for (int i = 0; i < 4; ++i) {
            float2 f = __half22float2(hp1[i]);
            a[8 + 2 * i]     = fmaf(w, f.x, a[8 + 2 * i]);
            a[8 + 2 * i + 1] = fmaf(w, f.y, a[8 + 2 * i + 1]);
        }
        avc = avn; hc0 = hn0; hc1 = hn1; cn = cf;
    }
#pragma unroll
    for (int off = 8; off < 64; off <<= 1) {
        s += __shfl_xor(s, off);
#pragma unroll
        for (int i = 0; i < 16; ++i) a[i] += __shfl_xor(a[i], off);
    }
    if (g == 0) {
        float inv = 1.0f / s;
#pragma unroll
        for (int q = 0; q < 4; ++q) {
            float4 bb = ((const float4*)b2)[gl * 4 + q];
            ((float4*)dout)[(size_t)node * 32 + gl * 4 + q] =
                make_float4(a[4 * q]     * inv + bb.x, a[4 * q + 1] * inv + bb.y,
                            a[4 * q + 2] * inv + bb.z, a[4 * q + 3] * inv + bb.w);
        }
    }
}

extern "C" void kernel_launch(void* const* d_in, const int* in_sizes, int n_in,
                              void* d_out, int out_size, void* d_ws, size_t ws_size,
                              hipStream_t stream) {
    const float* x      = (const float*)d_in[0];
    const int*   ei     = (const int*)  d_in[1];
    const float* W1     = (const float*)d_in[2];
    const float* a_src1 = (const float*)d_in[3];
    const float* a_dst1 = (const float*)d_in[4];
    const float* b1     = (const float*)d_in[5];
    const float* W2     = (const float*)d_in[6];
    const float* a_src2 = (const float*)d_in[7];
    const float* a_dst2 = (const float*)d_in[8];
    const float* b2     = (const float*)d_in[9];
    float* dout = (float*)d_out;

    const int N  = in_sizes[0] / 128;
    const int E  = in_sizes[1] / 2;
    const int ET = E + N;                 // edges + self loops
    const int NBUCK = (N + 255) >> 8;     // 196 for N=50000 (<=256 required)
    const int NBLKA = (ET + 4095) >> 12;  // pass-A/0 blocks

    char* wsb = (char*)d_ws;
    _Float16* h1 = (_Float16*)wsb; wsb += (size_t)N * 64 * 2;
    _Float16* h2 = (_Float16*)wsb; wsb += (size_t)N * 128 * 2;
    float* av1  = (float*)wsb; wsb += (size_t)N * 8 * 4;
    float* bv1  = (float*)wsb; wsb += (size_t)N * 8 * 4;
    float* out1 = (float*)wsb; wsb += (size_t)N * 64 * 4;
    float* av2  = (float*)wsb; wsb += (size_t)N * 4;
    float* bv2  = (float*)wsb; wsb += (size_t)N * 4;
    int* row_ptr = (int*)wsb; wsb += (size_t)(N + 1) * 4;
    int* col     = (int*)wsb; wsb += (size_t)ET * 4;
    unsigned int* bstore = (unsigned int*)wsb; wsb += (size_t)ET * 4;
    int* bcnt  = (int*)wsb; wsb += 256 * 4;
    int* bbase = (int*)wsb; wsb += 256 * 4;
    int* bcur  = (int*)wsb; wsb += 256 * 4;

    const int B = 256;
    const int gblocks = (N + 63) / 64;

    // ---- CSR build (bucket two-pass) ----
    zero_bcnt<<<1, B, 0, stream>>>(bcnt, NBUCK);
    bucket_count<<<NBLKA, B, 0, stream>>>(ei, E, ET, bcnt);
    bucket_scan<<<1, B, 0, stream>>>(bcnt, bbase, bcur, row_ptr, NBUCK, N, ET);
    bucket_scatter<<<NBLKA, B, 0, stream>>>(ei, E, ET, bcur, bstore, NBUCK);
    bucket_csr<<<NBUCK, B, 0, stream>>>(bstore, bcnt, bbase, row_ptr, col, N);

    // ---- layer 1 ----
    gemm1_kernel<<<gblocks, B, 0, stream>>>(x, W1, a_src1, a_dst1, h1, av1, bv1, N);
    agg1_kernel<<<(N + 3) / 4, B, 0, stream>>>(row_ptr, col, av1, bv1, (const __half*)h1, b1, out1, N);

    // ---- layer 2 ----
    gemm2_kernel<<<gblocks, B, 0, stream>>>(out1, W2, a_src2, a_dst2, h2, av2, bv2, N);
    agg2_kernel<<<(N + 3) / 4, B, 0, stream>>>(row_ptr, col, av2, bv2, (const __half*)h2, b2, dout, N);
}

// Round 10
// 220.800 us; speedup vs baseline: 1.0658x; 1.0658x over previous
//
#include <hip/hip_runtime.h>
#include <hip/hip_fp16.h>
#include <math.h>

#define NEG_SLOPE 0.2f

typedef _Float16 f16x8 __attribute__((ext_vector_type(8)));
typedef float    f32x4 __attribute__((ext_vector_type(4)));

__device__ __forceinline__ void get_edge(const int* __restrict__ ei, int E, int e,
                                         int& s, int& d) {
    if (e < E) { s = ei[e]; d = ei[E + e]; }
    else       { s = e - E; d = e - E; }
}

// ================= CSR build: bucket two-pass, no device-scope random atomics ==========
__global__ void zero_bcnt(int* __restrict__ bcnt, int nbuck) {
    if (threadIdx.x < nbuck) bcnt[threadIdx.x] = 0;
}

__global__ __launch_bounds__(256) void bucket_count(const int* __restrict__ ei, int E, int ET,
                                                    int* __restrict__ bcnt) {
    __shared__ int lhist[256];
    int t = threadIdx.x;
    lhist[t] = 0;
    __syncthreads();
    int start = blockIdx.x * 4096;
#pragma unroll
    for (int k = 0; k < 16; ++k) {
        int e = start + t + k * 256;
        if (e < ET) { int s, d; get_edge(ei, E, e, s, d); atomicAdd(&lhist[d >> 8], 1); }
    }
    __syncthreads();
    if (lhist[t] > 0) atomicAdd(&bcnt[t], lhist[t]);
}

__global__ void bucket_scan(const int* __restrict__ bcnt, int* __restrict__ bbase,
                            int* __restrict__ bcur, int* __restrict__ row_ptr,
                            int nbuck, int N, int ET) {
    __shared__ int buf[256];
    int t = threadIdx.x;
    int v = (t < nbuck) ? bcnt[t] : 0;
    buf[t] = v;
    __syncthreads();
    for (int off = 1; off < 256; off <<= 1) {
        int u = (t >= off) ? buf[t - off] : 0;
        __syncthreads();
        buf[t] += u;
        __syncthreads();
    }
    if (t < nbuck) { int ex = buf[t] - v; bbase[t] = ex; bcur[t] = ex; }
    if (t == 0) row_ptr[N] = ET;
}

__global__ __launch_bounds__(256) void bucket_scatter(const int* __restrict__ ei, int E, int ET,
                                                      int* __restrict__ bcur,
                                                      unsigned int* __restrict__ bstore,
                                                      int nbuck) {
    __shared__ int lhist[256], lbase[256], lrank[256], gbase[256];
    __shared__ unsigned int sbuf[4096];
    __shared__ int saddr[4096];
    int t = threadIdx.x;
    int start = blockIdx.x * 4096;
    int cnt = ET - start; if (cnt > 4096) cnt = 4096;
    lhist[t] = 0; lrank[t] = 0;
    __syncthreads();
    int mybuck[16]; unsigned int myval[16];
#pragma unroll
    for (int k = 0; k < 16; ++k) {
        int e = start + t + k * 256;
        mybuck[k] = -1;
        if (e < ET) {
            int s, d; get_edge(ei, E, e, s, d);
            mybuck[k] = d >> 8;
            myval[k] = ((unsigned int)d << 16) | (unsigned int)s;
            atomicAdd(&lhist[mybuck[k]], 1);
        }
    }
    __syncthreads();
    int v = lhist[t];
    lbase[t] = v;
    __syncthreads();
    for (int off = 1; off < 256; off <<= 1) {
        int u = (t >= off) ? lbase[t - off] : 0;
        __syncthreads();
        lbase[t] += u;
        __syncthreads();
    }
    int excl = lbase[t] - v;
    if (t < nbuck && v > 0) gbase[t] = atomicAdd(&bcur[t], v);
    __syncthreads();
    lbase[t] = excl;
    __syncthreads();
#pragma unroll
    for (int k = 0; k < 16; ++k) {
        int b = mybuck[k];
        if (b >= 0) {
            int r = atomicAdd(&lrank[b], 1);
            int idx = lbase[b] + r;
            sbuf[idx] = myval[k];
            saddr[idx] = gbase[b] + r;
        }
    }
    __syncthreads();
    for (int j = t; j < cnt; j += 256)
        bstore[saddr[j]] = sbuf[j];
}

__global__ __launch_bounds__(256) void bucket_csr(const unsigned int* __restrict__ bstore,
                                                  const int* __restrict__ bcnt,
                                                  const int* __restrict__ bbase,
                                                  int* __restrict__ row_ptr,
                                                  int* __restrict__ col, int N) {
    __shared__ int lcnt[256], lexcl[256], lrank[256];
    int b = blockIdx.x, t = threadIdx.x;
    int nb = bcnt[b], base = bbase[b];
    lcnt[t] = 0; lrank[t] = 0;
    __syncthreads();
    for (int i = t; i < nb; i += 256)
        atomicAdd(&lcnt[(bstore[base + i] >> 16) & 255], 1);
    __syncthreads();
    int v = lcnt[t];
    lexcl[t] = v;
    __syncthreads();
    for (int off = 1; off < 256; off <<= 1) {
        int u = (t >= off) ? lexcl[t - off] : 0;
        __syncthreads();
        lexcl[t] += u;
        __syncthreads();
    }
    int ex = lexcl[t] - v;
    __syncthreads();
    lexcl[t] = ex;
    __syncthreads();
    int node = (b << 8) + t;
    if (node < N) row_ptr[node] = base + ex;
    for (int i = t; i < nb; i += 256) {
        unsigned int pk = bstore[base + i];
        int d8 = (pk >> 16) & 255;
        int r = atomicAdd(&lrank[d8], 1);
        col[base + lexcl[d8] + r] = (int)(pk & 0xFFFFu);
    }
}

// ========== GEMM1 (MFMA f16): h1[N,64](f16) = x[N,128] @ W1[128,64] + att1 ==========
__global__ __launch_bounds__(256) void gemm1_kernel(const float* __restrict__ x,
                                                    const float* __restrict__ W,
                                                    const float* __restrict__ asrc,
                                                    const float* __restrict__ adst,
                                                    _Float16* __restrict__ hout,
                                                    float* __restrict__ av,
                                                    float* __restrict__ bv, int N) {
    __shared__ unsigned int sWu[4096];  // 16 frags * 64 lanes * 4 uints (16 KB)
    for (int p = threadIdx.x; p < 4096; p += 256) {
        int frag = p >> 8;
        int lane = (p >> 2) & 63;
        int j2   = p & 3;
        int chunk = frag >> 2, nt = frag & 3;
        int k = chunk * 32 + ((lane >> 4) << 3) + (j2 << 1);
        int n = nt * 16 + (lane & 15);
        union { _Float16 h[2]; unsigned int u; } pk;
        pk.h[0] = (_Float16)W[k * 64 + n];
        pk.h[1] = (_Float16)W[(k + 1) * 64 + n];
        sWu[p] = pk.u;
    }
    __syncthreads();

    int lane = threadIdx.x & 63;
    int wid  = threadIdx.x >> 6;
    int rbase = blockIdx.x * 64 + wid * 16;
    int l15 = lane & 15, quad = lane >> 4;
    int rA = rbase + l15; if (rA >= N) rA = N - 1;

    const unsigned int* fragbase = &sWu[lane * 4];
    f32x4 z = {0.f, 0.f, 0.f, 0.f};
    f32x4 acc[4] = {z, z, z, z};

#pragma unroll
    for (int chunk = 0; chunk < 4; ++chunk) {
        const float* xp = x + (size_t)rA * 128 + chunk * 32 + quad * 8;
        float4 f0 = *((const float4*)xp);
        float4 f1 = *((const float4*)(xp + 4));
        f16x8 af;
        af[0] = (_Float16)f0.x; af[1] = (_Float16)f0.y;
        af[2] = (_Float16)f0.z; af[3] = (_Float16)f0.w;
        af[4] = (_Float16)f1.x; af[5] = (_Float16)f1.y;
        af[6] = (_Float16)f1.z; af[7] = (_Float16)f1.w;
#pragma unroll
        for (int t = 0; t < 4; ++t) {
            f16x8 bf = *((const f16x8*)(fragbase + (chunk * 4 + t) * 256));
            acc[t] = __builtin_amdgcn_mfma_f32_16x16x32_f16(af, bf, acc[t], 0, 0, 0);
        }
    }

    float asc[4], adc[4];
#pragma unroll
    for (int t = 0; t < 4; ++t) { asc[t] = asrc[t * 16 + l15]; adc[t] = adst[t * 16 + l15]; }
#pragma unroll
    for (int reg = 0; reg < 4; ++reg) {
        int r = rbase + quad * 4 + reg;
        bool ok = (r < N);
#pragma unroll
        for (int t = 0; t < 4; ++t) {
            float v = acc[t][reg];
            if (ok) hout[(size_t)r * 64 + t * 16 + l15] = (_Float16)v;
            float pa = v * asc[t], pb = v * adc[t];
            pa += __shfl_xor(pa, 1); pb += __shfl_xor(pb, 1);
            pa += __shfl_xor(pa, 2); pb += __shfl_xor(pb, 2);
            pa += __shfl_xor(pa, 4); pb += __shfl_xor(pb, 4);
            if (ok && (lane & 7) == 0) {
                int head = t * 2 + (l15 >> 3);
                av[r * 8 + head] = pa;
                bv[r * 8 + head] = pb;
            }
        }
    }
}

// ========== fused layer-1 softmax-aggregate (R7 structure: 8 groups x 8 lanes) ==========
// Wave = 1 node; 8 groups of 8 lanes own edges e = beg+g, step 8.
// Lane (gl) covers channels 8gl..8gl+7 (16 B of the 128-B row); head = gl.
// Depth-2 pipeline, guarded prefetch -> up to 16 row-gathers in flight per wave.
__global__ __launch_bounds__(256) void agg1_kernel(const int* __restrict__ rp,
                                                   const int* __restrict__ col,
                                                   const float* __restrict__ av,
                                                   const float* __restrict__ bv,
                                                   const __half* __restrict__ h1,
                                                   const float* __restrict__ b1,
                                                   float* __restrict__ out1, int N) {
    int node = blockIdx.x * 4 + (threadIdx.x >> 6);
    int lane = threadIdx.x & 63;
    if (node >= N) return;
    int g = lane >> 3, gl = lane & 7;
    int beg = rp[node], end = rp[node + 1];
    int last = end - 1;
    float bd = bv[node * 8 + gl];
    const uint4* hrow = (const uint4*)h1;     // row stride = 8 uint4 (64 halfs)

    int e  = beg + g;
    uint4 zero4 = {0u, 0u, 0u, 0u};
    int c = col[e <= last ? e : last];
    int e2 = e + 8;
    int cn = col[e2 <= last ? e2 : last];
    float avc = 0.f; uint4 hc = zero4;
    if (e < end) { avc = av[c * 8 + gl]; hc = hrow[(size_t)c * 8 + gl]; }

    float s = 0.f, a0 = 0.f, a1 = 0.f, a2 = 0.f, a3 = 0.f,
          a4 = 0.f, a5 = 0.f, a6 = 0.f, a7 = 0.f;
    for (; e < end; e += 8) {
        int en = e + 8;
        float avn = 0.f; uint4 hn = zero4;
        if (en < end) { avn = av[cn * 8 + gl]; hn = hrow[(size_t)cn * 8 + gl]; }
        int ef = en + 8;
        int cf = col[ef <= last ? ef : last];
        float l = avc + bd;
        l = l > 0.f ? l : NEG_SLOPE * l;
        float w = __expf(l);
        float2 f0 = __half22float2(*(const __half2*)&hc.x);
        float2 f1 = __half22float2(*(const __half2*)&hc.y);
        float2 f2 = __half22float2(*(const __half2*)&hc.z);
        float2 f3 = __half22float2(*(const __half2*)&hc.w);
        s += w;
        a0 = fmaf(w, f0.x, a0); a1 = fmaf(w, f0.y, a1);
        a2 = fmaf(w, f1.x, a2); a3 = fmaf(w, f1.y, a3);
        a4 = fmaf(w, f2.x, a4); a5 = fmaf(w, f2.y, a5);
        a6 = fmaf(w, f3.x, a6); a7 = fmaf(w, f3.y, a7);
        avc = avn; hc = hn; cn = cf;
    }
#pragma unroll
    for (int off = 8; off < 64; off <<= 1) {
        s  += __shfl_xor(s, off);
        a0 += __shfl_xor(a0, off); a1 += __shfl_xor(a1, off);
        a2 += __shfl_xor(a2, off); a3 += __shfl_xor(a3, off);
        a4 += __shfl_xor(a4, off); a5 += __shfl_xor(a5, off);
        a6 += __shfl_xor(a6, off); a7 += __shfl_xor(a7, off);
    }
    if (g == 0) {
        float inv = 1.0f / s;
        float4 bb0 = ((const float4*)b1)[gl * 2];
        float4 bb1 = ((const float4*)b1)[gl * 2 + 1];
        float v0 = a0 * inv + bb0.x, v1 = a1 * inv + bb0.y;
        float v2 = a2 * inv + bb0.z, v3 = a3 * inv + bb0.w;
        float v4 = a4 * inv + bb1.x, v5 = a5 * inv + bb1.y;
        float v6 = a6 * inv + bb1.z, v7 = a7 * inv + bb1.w;
        v0 = v0 > 0.f ? v0 : expm1f(v0); v1 = v1 > 0.f ? v1 : expm1f(v1);
        v2 = v2 > 0.f ? v2 : expm1f(v2); v3 = v3 > 0.f ? v3 : expm1f(v3);
        v4 = v4 > 0.f ? v4 : expm1f(v4); v5 = v5 > 0.f ? v5 : expm1f(v5);
        v6 = v6 > 0.f ? v6 : expm1f(v6); v7 = v7 > 0.f ? v7 : expm1f(v7);
        ((float4*)out1)[(size_t)node * 16 + gl * 2]     = make_float4(v0, v1, v2, v3);
        ((float4*)out1)[(size_t)node * 16 + gl * 2 + 1] = make_float4(v4, v5, v6, v7);
    }
}

// ========== GEMM2 (MFMA f16): h2[N,128](f16) = out1[N,64] @ W2[64,128] + att2 ==========
__global__ __launch_bounds__(256) void gemm2_kernel(const float* __restrict__ he,
                                                    const float* __restrict__ W,
                                                    const float* __restrict__ asrc,
                                                    const float* __restrict__ adst,
                                                    _Float16* __restrict__ h2,
                                                    float* __restrict__ av,
                                                    float* __restrict__ bv, int N) {
    __shared__ unsigned int sWu[4096];  // 16 frags (16 KB)
    for (int p = threadIdx.x; p < 4096; p += 256) {
        int frag = p >> 8;
        int lane = (p >> 2) & 63;
        int j2   = p & 3;
        int chunk = frag >> 3, nt = frag & 7;
        int k = chunk * 32 + ((lane >> 4) << 3) + (j2 << 1);
        int n = nt * 16 + (lane & 15);
        union { _Float16 h[2]; unsigned int u; } pk;
        pk.h[0] = (_Float16)W[k * 128 + n];
        pk.h[1] = (_Float16)W[(k + 1) * 128 + n];
        sWu[p] = pk.u;
    }
    __syncthreads();

    int lane = threadIdx.x & 63;
    int wid  = threadIdx.x >> 6;
    int rbase = blockIdx.x * 64 + wid * 16;
    int l15 = lane & 15, quad = lane >> 4;
    int rA = rbase + l15; if (rA >= N) rA = N - 1;

    const unsigned int* fragbase = &sWu[lane * 4];
    f32x4 z = {0.f, 0.f, 0.f, 0.f};
    f32x4 acc[8] = {z, z, z, z, z, z, z, z};

#pragma unroll
    for (int chunk = 0; chunk < 2; ++chunk) {
        const float* xp = he + (size_t)rA * 64 + chunk * 32 + quad * 8;
        float4 f0 = *((const float4*)xp);
        float4 f1 = *((const float4*)(xp + 4));
        f16x8 af;
        af[0] = (_Float16)f0.x; af[1] = (_Float16)f0.y;
        af[2] = (_Float16)f0.z; af[3] = (_Float16)f0.w;
        af[4] = (_Float16)f1.x; af[5] = (_Float16)f1.y;
        af[6] = (_Float16)f1.z; af[7] = (_Float16)f1.w;
#pragma unroll
        for (int t = 0; t < 8; ++t) {
            f16x8 bf = *((const f16x8*)(fragbase + (chunk * 8 + t) * 256));
            acc[t] = __builtin_amdgcn_mfma_f32_16x16x32_f16(af, bf, acc[t], 0, 0, 0);
        }
    }

    float asc[8], adc[8];
#pragma unroll
    for (int t = 0; t < 8; ++t) { asc[t] = asrc[t * 16 + l15]; adc[t] = adst[t * 16 + l15]; }
#pragma unroll
    for (int reg = 0; reg < 4; ++reg) {
        int r = rbase + quad * 4 + reg;
        bool ok = (r < N);
        float pa = 0.0f, pb = 0.0f;
#pragma unroll
        for (int t = 0; t < 8; ++t) {
            float v = acc[t][reg];
            if (ok) h2[(size_t)r * 128 + t * 16 + l15] = (_Float16)v;
            pa = fmaf(v, asc[t], pa);
            pb = fmaf(v, adc[t], pb);
        }
        pa += __shfl_xor(pa, 1); pb += __shfl_xor(pb, 1);
        pa += __shfl_xor(pa, 2); pb += __shfl_xor(pb, 2);
        pa += __shfl_xor(pa, 4); pb += __shfl_xor(pb, 4);
        pa += __shfl_xor(pa, 8); pb += __shfl_xor(pb, 8);
        if (ok && l15 == 0) { av[r] = pa; bv[r] = pb; }
    }
}

// ========== fused layer-2 softmax-aggregate ==========
// Wave = 1 node; 8 groups of 8 lanes own edges e = beg+g, step 8.
// Lane (gl) covers halfs 16gl..16gl+15 (32 B of the 256-B row).
// Depth-2 pipeline -> ~16 row-gathers in flight per wave.
__global__ __launch_bounds__(256) void agg2_kernel(const int* __restrict__ rp,
                                                   const int* __restrict__ col,
                                                   const float* __restrict__ av,
                                                   const float* __restrict__ bv,
                                                   const __half* __restrict__ h2,
                                                   const float* __restrict__ b2,
                                                   float* __restrict__ dout, int N) {
    int node = blockIdx.x * 4 + (threadIdx.x >> 6);
    int lane = threadIdx.x & 63;
    if (node >= N) return;
    int g = lane >> 3, gl = lane & 7;
    int beg = rp[node], end = rp[node + 1];
    int last = end - 1;
    float bd = bv[node];
    const uint4* hrow = (const uint4*)h2;     // 16 uint4 per row

    uint4 z4 = {0u, 0u, 0u, 0u};
    int e  = beg + g;
    int c  = col[e <= last ? e : last];
    int e2 = e + 8;
    int cn = col[e2 <= last ? e2 : last];
    float avc = 0.f;
    uint4 hc0 = z4, hc1 = z4;
    if (e < end) {
        avc = av[c];
        hc0 = hrow[(size_t)c * 16 + gl * 2];
        hc1 = hrow[(size_t)c * 16 + gl * 2 + 1];
    }

    float s = 0.f, a[16];
#pragma unroll
    for (int i = 0; i < 16; ++i) a[i] = 0.f;
    for (; e < end; e += 8) {
        int en = e + 8;
        float avn = 0.f;
        uint4 hn0 = z4, hn1 = z4;
        if (en < end) {
            avn = av[cn];
            hn0 = hrow[(size_t)cn * 16 + gl * 2];
            hn1 = hrow[(size_t)cn * 16 + gl * 2 + 1];
        }
        int ef = en + 8;
        int cf = col[ef <= last ? ef : last];
        float l = avc + bd;
        l = l > 0.f ? l : NEG_SLOPE * l;
        float w = __expf(l);
        s += w;
        const __half2* hp0 = (const __half2*)&hc0;
        const __half2* hp1 = (const __half2*)&hc1;
#pragma unroll
        for (int i = 0; i < 4; ++i) {
            float2 f = __half22float2(hp0[i]);
            a[2 * i]     = fmaf(w, f.x, a[2 * i]);
            a[2 * i + 1] = fmaf(w, f.y, a[2 * i + 1]);
        }
#pragma unroll
        for (int i = 0; i < 4; ++i) {
            float2 f = __half22float2(hp1[i]);
            a[8 + 2 * i]     = fmaf(w, f.x, a[8 + 2 * i]);
            a[8 + 2 * i + 1] = fmaf(w, f.y, a[8 + 2 * i + 1]);
        }
        avc = avn; hc0 = hn0; hc1 = hn1; cn = cf;
    }
#pragma unroll
    for (int off = 8; off < 64; off <<= 1) {
        s += __shfl_xor(s, off);
#pragma unroll
        for (int i = 0; i < 16; ++i) a[i] += __shfl_xor(a[i], off);
    }
    if (g == 0) {
        float inv = 1.0f / s;
#pragma unroll
        for (int q = 0; q < 4; ++q) {
            float4 bb = ((const float4*)b2)[gl * 4 + q];
            ((float4*)dout)[(size_t)node * 32 + gl * 4 + q] =
                make_float4(a[4 * q]     * inv + bb.x, a[4 * q + 1] * inv + bb.y,
                            a[4 * q + 2] * inv + bb.z, a[4 * q + 3] * inv + bb.w);
        }
    }
}

extern "C" void kernel_launch(void* const* d_in, const int* in_sizes, int n_in,
                              void* d_out, int out_size, void* d_ws, size_t ws_size,
                              hipStream_t stream) {
    const float* x      = (const float*)d_in[0];
    const int*   ei     = (const int*)  d_in[1];
    const float* W1     = (const float*)d_in[2];
    const float* a_src1 = (const float*)d_in[3];
    const float* a_dst1 = (const float*)d_in[4];
    const float* b1     = (const float*)d_in[5];
    const float* W2     = (const float*)d_in[6];
    const float* a_src2 = (const float*)d_in[7];
    const float* a_dst2 = (const float*)d_in[8];
    const float* b2     = (const float*)d_in[9];
    float* dout = (float*)d_out;

    const int N  = in_sizes[0] / 128;
    const int E  = in_sizes[1] / 2;
    const int ET = E + N;                 // edges + self loops
    const int NBUCK = (N + 255) >> 8;     // 196 for N=50000 (<=256 required)
    const int NBLKA = (ET + 4095) >> 12;  // pass-A/0 blocks

    char* wsb = (char*)d_ws;
    _Float16* h1 = (_Float16*)wsb; wsb += (size_t)N * 64 * 2;
    _Float16* h2 = (_Float16*)wsb; wsb += (size_t)N * 128 * 2;
    float* av1  = (float*)wsb; wsb += (size_t)N * 8 * 4;
    float* bv1  = (float*)wsb; wsb += (size_t)N * 8 * 4;
    float* out1 = (float*)wsb; wsb += (size_t)N * 64 * 4;
    float* av2  = (float*)wsb; wsb += (size_t)N * 4;
    float* bv2  = (float*)wsb; wsb += (size_t)N * 4;
    int* row_ptr = (int*)wsb; wsb += (size_t)(N + 1) * 4;
    int* col     = (int*)wsb; wsb += (size_t)ET * 4;
    unsigned int* bstore = (unsigned int*)wsb; wsb += (size_t)ET * 4;
    int* bcnt  = (int*)wsb; wsb += 256 * 4;
    int* bbase = (int*)wsb; wsb += 256 * 4;
    int* bcur  = (int*)wsb; wsb += 256 * 4;

    const int B = 256;
    const int gblocks = (N + 63) / 64;

    // ---- CSR build (bucket two-pass) ----
    zero_bcnt<<<1, B, 0, stream>>>(bcnt, NBUCK);
    bucket_count<<<NBLKA, B, 0, stream>>>(ei, E, ET, bcnt);
    bucket_scan<<<1, B, 0, stream>>>(bcnt, bbase, bcur, row_ptr, NBUCK, N, ET);
    bucket_scatter<<<NBLKA, B, 0, stream>>>(ei, E, ET, bcur, bstore, NBUCK);
    bucket_csr<<<NBUCK, B, 0, stream>>>(bstore, bcnt, bbase, row_ptr, col, N);

    // ---- layer 1 ----
    gemm1_kernel<<<gblocks, B, 0, stream>>>(x, W1, a_src1, a_dst1, h1, av1, bv1, N);
    agg1_kernel<<<(N + 3) / 4, B, 0, stream>>>(row_ptr, col, av1, bv1, (const __half*)h1, b1, out1, N);

    // ---- layer 2 ----
    gemm2_kernel<<<gblocks, B, 0, stream>>>(out1, W2, a_src2, a_dst2, h2, av2, bv2, N);
    agg2_kernel<<<(N + 3) / 4, B, 0, stream>>>(row_ptr, col, av2, bv2, (const __half*)h2, b2, dout, N);
}

// Round 11
// 219.070 us; speedup vs baseline: 1.0742x; 1.0079x over previous
//
#include <hip/hip_runtime.h>
#include <hip/hip_fp16.h>
#include <math.h>

#define NEG_SLOPE 0.2f

typedef _Float16 f16x8 __attribute__((ext_vector_type(8)));
typedef float    f32x4 __attribute__((ext_vector_type(4)));

__device__ __forceinline__ void get_edge(const int* __restrict__ ei, int E, int e,
                                         int& s, int& d) {
    if (e < E) { s = ei[e]; d = ei[E + e]; }
    else       { s = e - E; d = e - E; }
}

// ================= CSR build: bucket two-pass, no device-scope random atomics ==========
__global__ void zero_bcnt(int* __restrict__ bcnt, int nbuck) {
    if (threadIdx.x < nbuck) bcnt[threadIdx.x] = 0;
}

__global__ __launch_bounds__(256) void bucket_count(const int* __restrict__ ei, int E, int ET,
                                                    int* __restrict__ bcnt) {
    __shared__ int lhist[256];
    int t = threadIdx.x;
    lhist[t] = 0;
    __syncthreads();
    int start = blockIdx.x * 4096;
#pragma unroll
    for (int k = 0; k < 16; ++k) {
        int e = start + t + k * 256;
        if (e < ET) { int s, d; get_edge(ei, E, e, s, d); atomicAdd(&lhist[d >> 8], 1); }
    }
    __syncthreads();
    if (lhist[t] > 0) atomicAdd(&bcnt[t], lhist[t]);
}

__global__ void bucket_scan(const int* __restrict__ bcnt, int* __restrict__ bbase,
                            int* __restrict__ bcur, int* __restrict__ row_ptr,
                            int nbuck, int N, int ET) {
    __shared__ int buf[256];
    int t = threadIdx.x;
    int v = (t < nbuck) ? bcnt[t] : 0;
    buf[t] = v;
    __syncthreads();
    for (int off = 1; off < 256; off <<= 1) {
        int u = (t >= off) ? buf[t - off] : 0;
        __syncthreads();
        buf[t] += u;
        __syncthreads();
    }
    if (t < nbuck) { int ex = buf[t] - v; bbase[t] = ex; bcur[t] = ex; }
    if (t == 0) row_ptr[N] = ET;
}

__global__ __launch_bounds__(256) void bucket_scatter(const int* __restrict__ ei, int E, int ET,
                                                      int* __restrict__ bcur,
                                                      unsigned int* __restrict__ bstore,
                                                      int nbuck) {
    __shared__ int lhist[256], lbase[256], lrank[256], gbase[256];
    __shared__ unsigned int sbuf[4096];
    __shared__ int saddr[4096];
    int t = threadIdx.x;
    int start = blockIdx.x * 4096;
    int cnt = ET - start; if (cnt > 4096) cnt = 4096;
    lhist[t] = 0; lrank[t] = 0;
    __syncthreads();
    int mybuck[16]; unsigned int myval[16];
#pragma unroll
    for (int k = 0; k < 16; ++k) {
        int e = start + t + k * 256;
        mybuck[k] = -1;
        if (e < ET) {
            int s, d; get_edge(ei, E, e, s, d);
            mybuck[k] = d >> 8;
            myval[k] = ((unsigned int)d << 16) | (unsigned int)s;
            atomicAdd(&lhist[mybuck[k]], 1);
        }
    }
    __syncthreads();
    int v = lhist[t];
    lbase[t] = v;
    __syncthreads();
    for (int off = 1; off < 256; off <<= 1) {
        int u = (t >= off) ? lbase[t - off] : 0;
        __syncthreads();
        lbase[t] += u;
        __syncthreads();
    }
    int excl = lbase[t] - v;
    if (t < nbuck && v > 0) gbase[t] = atomicAdd(&bcur[t], v);
    __syncthreads();
    lbase[t] = excl;
    __syncthreads();
#pragma unroll
    for (int k = 0; k < 16; ++k) {
        int b = mybuck[k];
        if (b >= 0) {
            int r = atomicAdd(&lrank[b], 1);
            int idx = lbase[b] + r;
            sbuf[idx] = myval[k];
            saddr[idx] = gbase[b] + r;
        }
    }
    __syncthreads();
    for (int j = t; j < cnt; j += 256)
        bstore[saddr[j]] = sbuf[j];
}

__global__ __launch_bounds__(256) void bucket_csr(const unsigned int* __restrict__ bstore,
                                                  const int* __restrict__ bcnt,
                                                  const int* __restrict__ bbase,
                                                  int* __restrict__ row_ptr,
                                                  int* __restrict__ col, int N) {
    __shared__ int lcnt[256], lexcl[256], lrank[256];
    int b = blockIdx.x, t = threadIdx.x;
    int nb = bcnt[b], base = bbase[b];
    lcnt[t] = 0; lrank[t] = 0;
    __syncthreads();
    for (int i = t; i < nb; i += 256)
        atomicAdd(&lcnt[(bstore[base + i] >> 16) & 255], 1);
    __syncthreads();
    int v = lcnt[t];
    lexcl[t] = v;
    __syncthreads();
    for (int off = 1; off < 256; off <<= 1) {
        int u = (t >= off) ? lexcl[t - off] : 0;
        __syncthreads();
        lexcl[t] += u;
        __syncthreads();
    }
    int ex = lexcl[t] - v;
    __syncthreads();
    lexcl[t] = ex;
    __syncthreads();
    int node = (b << 8) + t;
    if (node < N) row_ptr[node] = base + ex;
    for (int i = t; i < nb; i += 256) {
        unsigned int pk = bstore[base + i];
        int d8 = (pk >> 16) & 255;
        int r = atomicAdd(&lrank[d8], 1);
        col[base + lexcl[d8] + r] = (int)(pk & 0xFFFFu);
    }
}

// ========== proj_att2: wa = W2 @ a_src2, wb = W2 @ a_dst2  (layer-2 att in 64-dim) ====
__global__ void proj_att2(const float* __restrict__ W2, const float* __restrict__ as2,
                          const float* __restrict__ ad2, float* __restrict__ wa,
                          float* __restrict__ wb) {
    int k = threadIdx.x;  // 0..63
    const float* wr = W2 + k * 128;
    float sa = 0.f, sb = 0.f;
#pragma unroll 8
    for (int c = 0; c < 128; ++c) {
        float w = wr[c];
        sa = fmaf(w, as2[c], sa);
        sb = fmaf(w, ad2[c], sb);
    }
    wa[k] = sa; wb[k] = sb;
}

// ========== GEMM1 (MFMA f16): h1[N,64](f16) = x[N,128] @ W1[128,64] + att1 ==========
__global__ __launch_bounds__(256) void gemm1_kernel(const float* __restrict__ x,
                                                    const float* __restrict__ W,
                                                    const float* __restrict__ asrc,
                                                    const float* __restrict__ adst,
                                                    _Float16* __restrict__ hout,
                                                    float* __restrict__ av,
                                                    float* __restrict__ bv, int N) {
    __shared__ unsigned int sWu[4096];  // 16 frags * 64 lanes * 4 uints (16 KB)
    for (int p = threadIdx.x; p < 4096; p += 256) {
        int frag = p >> 8;
        int lane = (p >> 2) & 63;
        int j2   = p & 3;
        int chunk = frag >> 2, nt = frag & 3;
        int k = chunk * 32 + ((lane >> 4) << 3) + (j2 << 1);
        int n = nt * 16 + (lane & 15);
        union { _Float16 h[2]; unsigned int u; } pk;
        pk.h[0] = (_Float16)W[k * 64 + n];
        pk.h[1] = (_Float16)W[(k + 1) * 64 + n];
        sWu[p] = pk.u;
    }
    __syncthreads();

    int lane = threadIdx.x & 63;
    int wid  = threadIdx.x >> 6;
    int rbase = blockIdx.x * 64 + wid * 16;
    int l15 = lane & 15, quad = lane >> 4;
    int rA = rbase + l15; if (rA >= N) rA = N - 1;

    const unsigned int* fragbase = &sWu[lane * 4];
    f32x4 z = {0.f, 0.f, 0.f, 0.f};
    f32x4 acc[4] = {z, z, z, z};

#pragma unroll
    for (int chunk = 0; chunk < 4; ++chunk) {
        const float* xp = x + (size_t)rA * 128 + chunk * 32 + quad * 8;
        float4 f0 = *((const float4*)xp);
        float4 f1 = *((const float4*)(xp + 4));
        f16x8 af;
        af[0] = (_Float16)f0.x; af[1] = (_Float16)f0.y;
        af[2] = (_Float16)f0.z; af[3] = (_Float16)f0.w;
        af[4] = (_Float16)f1.x; af[5] = (_Float16)f1.y;
        af[6] = (_Float16)f1.z; af[7] = (_Float16)f1.w;
#pragma unroll
        for (int t = 0; t < 4; ++t) {
            f16x8 bf = *((const f16x8*)(fragbase + (chunk * 4 + t) * 256));
            acc[t] = __builtin_amdgcn_mfma_f32_16x16x32_f16(af, bf, acc[t], 0, 0, 0);
        }
    }

    float asc[4], adc[4];
#pragma unroll
    for (int t = 0; t < 4; ++t) { asc[t] = asrc[t * 16 + l15]; adc[t] = adst[t * 16 + l15]; }
#pragma unroll
    for (int reg = 0; reg < 4; ++reg) {
        int r = rbase + quad * 4 + reg;
        bool ok = (r < N);
#pragma unroll
        for (int t = 0; t < 4; ++t) {
            float v = acc[t][reg];
            if (ok) hout[(size_t)r * 64 + t * 16 + l15] = (_Float16)v;
            float pa = v * asc[t], pb = v * adc[t];
            pa += __shfl_xor(pa, 1); pb += __shfl_xor(pb, 1);
            pa += __shfl_xor(pa, 2); pb += __shfl_xor(pb, 2);
            pa += __shfl_xor(pa, 4); pb += __shfl_xor(pb, 4);
            if (ok && (lane & 7) == 0) {
                int head = t * 2 + (l15 >> 3);
                av[r * 8 + head] = pa;
                bv[r * 8 + head] = pb;
            }
        }
    }
}

// ========== fused layer-1 softmax-aggregate + layer-2 att coeffs ==========
// Wave = 1 node; 8 groups of 8 lanes own edges e = beg+g, step 8.
// Lane (gl) covers channels 8gl..8gl+7 (16 B of the 128-B fp16 row); head = gl.
// Epilogue: out1 fp16 + av2/bv2 = (ELU'd out1) . (W2@a_src2 / W2@a_dst2).
__global__ __launch_bounds__(256) void agg1_kernel(const int* __restrict__ rp,
                                                   const int* __restrict__ col,
                                                   const float* __restrict__ av,
                                                   const float* __restrict__ bv,
                                                   const __half* __restrict__ h1,
                                                   const float* __restrict__ b1,
                                                   const float* __restrict__ wa,
                                                   const float* __restrict__ wb,
                                                   _Float16* __restrict__ out1,
                                                   float* __restrict__ av2,
                                                   float* __restrict__ bv2, int N) {
    int node = blockIdx.x * 4 + (threadIdx.x >> 6);
    int lane = threadIdx.x & 63;
    if (node >= N) return;
    int g = lane >> 3, gl = lane & 7;
    int beg = rp[node], end = rp[node + 1];
    int last = end - 1;
    float bd = bv[node * 8 + gl];
    const uint4* hrow = (const uint4*)h1;     // row stride = 8 uint4 (64 halfs)

    int e  = beg + g;
    uint4 zero4 = {0u, 0u, 0u, 0u};
    int c = col[e <= last ? e : last];
    int e2 = e + 8;
    int cn = col[e2 <= last ? e2 : last];
    float avc = 0.f; uint4 hc = zero4;
    if (e < end) { avc = av[c * 8 + gl]; hc = hrow[(size_t)c * 8 + gl]; }

    float s = 0.f, a0 = 0.f, a1 = 0.f, a2 = 0.f, a3 = 0.f,
          a4 = 0.f, a5 = 0.f, a6 = 0.f, a7 = 0.f;
    for (; e < end; e += 8) {
        int en = e + 8;
        float avn = 0.f; uint4 hn = zero4;
        if (en < end) { avn = av[cn * 8 + gl]; hn = hrow[(size_t)cn * 8 + gl]; }
        int ef = en + 8;
        int cf = col[ef <= last ? ef : last];
        float l = avc + bd;
        l = l > 0.f ? l : NEG_SLOPE * l;
        float w = __expf(l);
        float2 f0 = __half22float2(*(const __half2*)&hc.x);
        float2 f1 = __half22float2(*(const __half2*)&hc.y);
        float2 f2 = __half22float2(*(const __half2*)&hc.z);
        float2 f3 = __half22float2(*(const __half2*)&hc.w);
        s += w;
        a0 = fmaf(w, f0.x, a0); a1 = fmaf(w, f0.y, a1);
        a2 = fmaf(w, f1.x, a2); a3 = fmaf(w, f1.y, a3);
        a4 = fmaf(w, f2.x, a4); a5 = fmaf(w, f2.y, a5);
        a6 = fmaf(w, f3.x, a6); a7 = fmaf(w, f3.y, a7);
        avc = avn; hc = hn; cn = cf;
    }
#pragma unroll
    for (int off = 8; off < 64; off <<= 1) {
        s  += __shfl_xor(s, off);
        a0 += __shfl_xor(a0, off); a1 += __shfl_xor(a1, off);
        a2 += __shfl_xor(a2, off); a3 += __shfl_xor(a3, off);
        a4 += __shfl_xor(a4, off); a5 += __shfl_xor(a5, off);
        a6 += __shfl_xor(a6, off); a7 += __shfl_xor(a7, off);
    }
    // every lane now holds the full totals for channels 8gl..8gl+7
    float inv = 1.0f / s;
    float4 bb0 = ((const float4*)b1)[gl * 2];
    float4 bb1 = ((const float4*)b1)[gl * 2 + 1];
    float v0 = a0 * inv + bb0.x, v1 = a1 * inv + bb0.y;
    float v2 = a2 * inv + bb0.z, v3 = a3 * inv + bb0.w;
    float v4 = a4 * inv + bb1.x, v5 = a5 * inv + bb1.y;
    float v6 = a6 * inv + bb1.z, v7 = a7 * inv + bb1.w;
    v0 = v0 > 0.f ? v0 : expm1f(v0); v1 = v1 > 0.f ? v1 : expm1f(v1);
    v2 = v2 > 0.f ? v2 : expm1f(v2); v3 = v3 > 0.f ? v3 : expm1f(v3);
    v4 = v4 > 0.f ? v4 : expm1f(v4); v5 = v5 > 0.f ? v5 : expm1f(v5);
    v6 = v6 > 0.f ? v6 : expm1f(v6); v7 = v7 > 0.f ? v7 : expm1f(v7);
    // layer-2 attention coefficients (dot with projected vectors)
    float4 wa0 = ((const float4*)wa)[gl * 2], wa1 = ((const float4*)wa)[gl * 2 + 1];
    float4 wb0 = ((const float4*)wb)[gl * 2], wb1 = ((const float4*)wb)[gl * 2 + 1];
    float pa = v0 * wa0.x + v1 * wa0.y + v2 * wa0.z + v3 * wa0.w
             + v4 * wa1.x + v5 * wa1.y + v6 * wa1.z + v7 * wa1.w;
    float pb = v0 * wb0.x + v1 * wb0.y + v2 * wb0.z + v3 * wb0.w
             + v4 * wb1.x + v5 * wb1.y + v6 * wb1.z + v7 * wb1.w;
    pa += __shfl_xor(pa, 1); pb += __shfl_xor(pb, 1);
    pa += __shfl_xor(pa, 2); pb += __shfl_xor(pb, 2);
    pa += __shfl_xor(pa, 4); pb += __shfl_xor(pb, 4);
    if (lane == 0) { av2[node] = pa; bv2[node] = pb; }
    if (g == 0) {
        f16x8 o;
        o[0] = (_Float16)v0; o[1] = (_Float16)v1; o[2] = (_Float16)v2; o[3] = (_Float16)v3;
        o[4] = (_Float16)v4; o[5] = (_Float16)v5; o[6] = (_Float16)v6; o[7] = (_Float16)v7;
        ((f16x8*)out1)[(size_t)node * 8 + gl] = o;
    }
}

// ========== fused layer-2 softmax-aggregate in 64-dim out1 space ==========
// Same 8x8 template; gathers 128-B fp16 out1 rows; writes normalized fp32 agg64.
__global__ __launch_bounds__(256) void agg2_kernel(const int* __restrict__ rp,
                                                   const int* __restrict__ col,
                                                   const float* __restrict__ av,
                                                   const float* __restrict__ bv,
                                                   const __half* __restrict__ out1,
                                                   float* __restrict__ agg64, int N) {
    int node = blockIdx.x * 4 + (threadIdx.x >> 6);
    int lane = threadIdx.x & 63;
    if (node >= N) return;
    int g = lane >> 3, gl = lane & 7;
    int beg = rp[node], end = rp[node + 1];
    int last = end - 1;
    float bd = bv[node];
    const uint4* hrow = (const uint4*)out1;   // row stride = 8 uint4 (64 halfs)

    int e  = beg + g;
    uint4 zero4 = {0u, 0u, 0u, 0u};
    int c = col[e <= last ? e : last];
    int e2 = e + 8;
    int cn = col[e2 <= last ? e2 : last];
    float avc = 0.f; uint4 hc = zero4;
    if (e < end) { avc = av[c]; hc = hrow[(size_t)c * 8 + gl]; }

    float s = 0.f, a0 = 0.f, a1 = 0.f, a2 = 0.f, a3 = 0.f,
          a4 = 0.f, a5 = 0.f, a6 = 0.f, a7 = 0.f;
    for (; e < end; e += 8) {
        int en = e + 8;
        float avn = 0.f; uint4 hn = zero4;
        if (en < end) { avn = av[cn]; hn = hrow[(size_t)cn * 8 + gl]; }
        int ef = en + 8;
        int cf = col[ef <= last ? ef : last];
        float l = avc + bd;
        l = l > 0.f ? l : NEG_SLOPE * l;
        float w = __expf(l);
        float2 f0 = __half22float2(*(const __half2*)&hc.x);
        float2 f1 = __half22float2(*(const __half2*)&hc.y);
        float2 f2 = __half22float2(*(const __half2*)&hc.z);
        float2 f3 = __half22float2(*(const __half2*)&hc.w);
        s += w;
        a0 = fmaf(w, f0.x, a0); a1 = fmaf(w, f0.y, a1);
        a2 = fmaf(w, f1.x, a2); a3 = fmaf(w, f1.y, a3);
        a4 = fmaf(w, f2.x, a4); a5 = fmaf(w, f2.y, a5);
        a6 = fmaf(w, f3.x, a6); a7 = fmaf(w, f3.y, a7);
        avc = avn; hc = hn; cn = cf;
    }
#pragma unroll
    for (int off = 8; off < 64; off <<= 1) {
        s  += __shfl_xor(s, off);
        a0 += __shfl_xor(a0, off); a1 += __shfl_xor(a1, off);
        a2 += __shfl_xor(a2, off); a3 += __shfl_xor(a3, off);
        a4 += __shfl_xor(a4, off); a5 += __shfl_xor(a5, off);
        a6 += __shfl_xor(a6, off); a7 += __shfl_xor(a7, off);
    }
    if (g == 0) {
        float inv = 1.0f / s;
        ((float4*)agg64)[(size_t)node * 16 + gl * 2] =
            make_float4(a0 * inv, a1 * inv, a2 * inv, a3 * inv);
        ((float4*)agg64)[(size_t)node * 16 + gl * 2 + 1] =
            make_float4(a4 * inv, a5 * inv, a6 * inv, a7 * inv);
    }
}

// ========== GEMM2 (MFMA f16): dout[N,128] = agg64[N,64] @ W2[64,128] + b2 ==========
__global__ __launch_bounds__(256) void gemm2_kernel(const float* __restrict__ he,
                                                    const float* __restrict__ W,
                                                    const float* __restrict__ b2,
                                                    float* __restrict__ dout, int N) {
    __shared__ unsigned int sWu[4096];  // 16 frags (16 KB)
    for (int p = threadIdx.x; p < 4096; p += 256) {
        int frag = p >> 8;
        int lane = (p >> 2) & 63;
        int j2   = p & 3;
        int chunk = frag >> 3, nt = frag & 7;
        int k = chunk * 32 + ((lane >> 4) << 3) + (j2 << 1);
        int n = nt * 16 + (lane & 15);
        union { _Float16 h[2]; unsigned int u; } pk;
        pk.h[0] = (_Float16)W[k * 128 + n];
        pk.h[1] = (_Float16)W[(k + 1) * 128 + n];
        sWu[p] = pk.u;
    }
    __syncthreads();

    int lane = threadIdx.x & 63;
    int wid  = threadIdx.x >> 6;
    int rbase = blockIdx.x * 64 + wid * 16;
    int l15 = lane & 15, quad = lane >> 4;
    int rA = rbase + l15; if (rA >= N) rA = N - 1;

    const unsigned int* fragbase = &sWu[lane * 4];
    f32x4 z = {0.f, 0.f, 0.f, 0.f};
    f32x4 acc[8] = {z, z, z, z, z, z, z, z};

#pragma unroll
    for (int chunk = 0; chunk < 2; ++chunk) {
        const float* xp = he + (size_t)rA * 64 + chunk * 32 + quad * 8;
        float4 f0 = *((const float4*)xp);
        float4 f1 = *((const float4*)(xp + 4));
        f16x8 af;
        af[0] = (_Float16)f0.x; af[1] = (_Float16)f0.y;
        af[2] = (_Float16)f0.z; af[3] = (_Float16)f0.w;
        af[4] = (_Float16)f1.x; af[5] = (_Float16)f1.y;
        af[6] = (_Float16)f1.z; af[7] = (_Float16)f1.w;
#pragma unroll
        for (int t = 0; t < 8; ++t) {
            f16x8 bf = *((const f16x8*)(fragbase + (chunk * 8 + t) * 256));
            acc[t] = __builtin_amdgcn_mfma_f32_16x16x32_f16(af, bf, acc[t], 0, 0, 0);
        }
    }

    float bcol[8];
#pragma unroll
    for (int t = 0; t < 8; ++t) bcol[t] = b2[t * 16 + l15];
#pragma unroll
    for (int reg = 0; reg < 4; ++reg) {
        int r = rbase + quad * 4 + reg;
        if (r < N) {
#pragma unroll
            for (int t = 0; t < 8; ++t)
                dout[(size_t)r * 128 + t * 16 + l15] = acc[t][reg] + bcol[t];
        }
    }
}

extern "C" void kernel_launch(void* const* d_in, const int* in_sizes, int n_in,
                              void* d_out, int out_size, void* d_ws, size_t ws_size,
                              hipStream_t stream) {
    const float* x      = (const float*)d_in[0];
    const int*   ei     = (const int*)  d_in[1];
    const float* W1     = (const float*)d_in[2];
    const float* a_src1 = (const float*)d_in[3];
    const float* a_dst1 = (const float*)d_in[4];
    const float* b1     = (const float*)d_in[5];
    const float* W2     = (const float*)d_in[6];
    const float* a_src2 = (const float*)d_in[7];
    const float* a_dst2 = (const float*)d_in[8];
    const float* b2     = (const float*)d_in[9];
    float* dout = (float*)d_out;

    const int N  = in_sizes[0] / 128;
    const int E  = in_sizes[1] / 2;
    const int ET = E + N;                 // edges + self loops
    const int NBUCK = (N + 255) >> 8;     // 196 for N=50000 (<=256 required)
    const int NBLKA = (ET + 4095) >> 12;  // pass-A/0 blocks

    char* wsb = (char*)d_ws;
    _Float16* h1   = (_Float16*)wsb; wsb += (size_t)N * 64 * 2;
    _Float16* out1 = (_Float16*)wsb; wsb += (size_t)N * 64 * 2;
    float* agg64 = (float*)wsb; wsb += (size_t)N * 64 * 4;
    float* av1  = (float*)wsb; wsb += (size_t)N * 8 * 4;
    float* bv1  = (float*)wsb; wsb += (size_t)N * 8 * 4;
    float* av2  = (float*)wsb; wsb += (size_t)N * 4;
    float* bv2  = (float*)wsb; wsb += (size_t)N * 4;
    float* wa   = (float*)wsb; wsb += 64 * 4;
    float* wb   = (float*)wsb; wsb += 64 * 4;
    int* row_ptr = (int*)wsb; wsb += (size_t)(N + 1) * 4;
    int* col     = (int*)wsb; wsb += (size_t)ET * 4;
    unsigned int* bstore = (unsigned int*)wsb; wsb += (size_t)ET * 4;
    int* bcnt  = (int*)wsb; wsb += 256 * 4;
    int* bbase = (int*)wsb; wsb += 256 * 4;
    int* bcur  = (int*)wsb; wsb += 256 * 4;

    const int B = 256;
    const int gblocks = (N + 63) / 64;

    // ---- CSR build (bucket two-pass) ----
    zero_bcnt<<<1, B, 0, stream>>>(bcnt, NBUCK);
    bucket_count<<<NBLKA, B, 0, stream>>>(ei, E, ET, bcnt);
    bucket_scan<<<1, B, 0, stream>>>(bcnt, bbase, bcur, row_ptr, NBUCK, N, ET);
    bucket_scatter<<<NBLKA, B, 0, stream>>>(ei, E, ET, bcur, bstore, NBUCK);
    bucket_csr<<<NBUCK, B, 0, stream>>>(bstore, bcnt, bbase, row_ptr, col, N);

    // ---- layer-2 att projection (independent, tiny) ----
    proj_att2<<<1, 64, 0, stream>>>(W2, a_src2, a_dst2, wa, wb);

    // ---- layer 1 ----
    gemm1_kernel<<<gblocks, B, 0, stream>>>(x, W1, a_src1, a_dst1, h1, av1, bv1, N);
    agg1_kernel<<<(N + 3) / 4, B, 0, stream>>>(row_ptr, col, av1, bv1, (const __half*)h1,
                                               b1, wa, wb, out1, av2, bv2, N);

    // ---- layer 2 (aggregate in 64-dim, then GEMM) ----
    agg2_kernel<<<(N + 3) / 4, B, 0, stream>>>(row_ptr, col, av2, bv2,
                                               (const __half*)out1, agg64, N);
    gemm2_kernel<<<gblocks, B, 0, stream>>>(agg64, W2, b2, dout, N);
}

// Round 12
// 219.059 us; speedup vs baseline: 1.0743x; 1.0000x over previous
//
#include <hip/hip_runtime.h>
#include <hip/hip_fp16.h>
#include <math.h>

#define NEG_SLOPE 0.2f

typedef _Float16 f16x8 __attribute__((ext_vector_type(8)));
typedef float    f32x4 __attribute__((ext_vector_type(4)));

__device__ __forceinline__ void get_edge(const int* __restrict__ ei, int E, int e,
                                         int& s, int& d) {
    if (e < E) { s = ei[e]; d = ei[E + e]; }
    else       { s = e - E; d = e - E; }
}

// ================= CSR build: bucket two-pass, no device-scope random atomics ==========
__global__ __launch_bounds__(256) void bucket_count(const int* __restrict__ ei, int E, int ET,
                                                    int* __restrict__ bcnt) {
    __shared__ int lhist[256];
    int t = threadIdx.x;
    lhist[t] = 0;
    __syncthreads();
    int start = blockIdx.x * 4096;
#pragma unroll
    for (int k = 0; k < 16; ++k) {
        int e = start + t + k * 256;
        if (e < ET) { int s, d; get_edge(ei, E, e, s, d); atomicAdd(&lhist[d >> 8], 1); }
    }
    __syncthreads();
    if (lhist[t] > 0) atomicAdd(&bcnt[t], lhist[t]);
}

__global__ void bucket_scan(const int* __restrict__ bcnt, int* __restrict__ bbase,
                            int* __restrict__ bcur, int* __restrict__ row_ptr,
                            int nbuck, int N, int ET) {
    __shared__ int buf[256];
    int t = threadIdx.x;
    int v = (t < nbuck) ? bcnt[t] : 0;
    buf[t] = v;
    __syncthreads();
    for (int off = 1; off < 256; off <<= 1) {
        int u = (t >= off) ? buf[t - off] : 0;
        __syncthreads();
        buf[t] += u;
        __syncthreads();
    }
    if (t < nbuck) { int ex = buf[t] - v; bbase[t] = ex; bcur[t] = ex; }
    if (t == 0) row_ptr[N] = ET;
}

__global__ __launch_bounds__(256) void bucket_scatter(const int* __restrict__ ei, int E, int ET,
                                                      int* __restrict__ bcur,
                                                      unsigned int* __restrict__ bstore,
                                                      int nbuck) {
    __shared__ int lhist[256], lbase[256], lrank[256], gbase[256];
    __shared__ unsigned int sbuf[4096];
    __shared__ int saddr[4096];
    int t = threadIdx.x;
    int start = blockIdx.x * 4096;
    int cnt = ET - start; if (cnt > 4096) cnt = 4096;
    lhist[t] = 0; lrank[t] = 0;
    __syncthreads();
    int mybuck[16]; unsigned int myval[16];
#pragma unroll
    for (int k = 0; k < 16; ++k) {
        int e = start + t + k * 256;
        mybuck[k] = -1;
        if (e < ET) {
            int s, d; get_edge(ei, E, e, s, d);
            mybuck[k] = d >> 8;
            myval[k] = ((unsigned int)d << 16) | (unsigned int)s;
            atomicAdd(&lhist[mybuck[k]], 1);
        }
    }
    __syncthreads();
    int v = lhist[t];
    lbase[t] = v;
    __syncthreads();
    for (int off = 1; off < 256; off <<= 1) {
        int u = (t >= off) ? lbase[t - off] : 0;
        __syncthreads();
        lbase[t] += u;
        __syncthreads();
    }
    int excl = lbase[t] - v;
    if (t < nbuck && v > 0) gbase[t] = atomicAdd(&bcur[t], v);
    __syncthreads();
    lbase[t] = excl;
    __syncthreads();
#pragma unroll
    for (int k = 0; k < 16; ++k) {
        int b = mybuck[k];
        if (b >= 0) {
            int r = atomicAdd(&lrank[b], 1);
            int idx = lbase[b] + r;
            sbuf[idx] = myval[k];
            saddr[idx] = gbase[b] + r;
        }
    }
    __syncthreads();
    for (int j = t; j < cnt; j += 256)
        bstore[saddr[j]] = sbuf[j];
}

__global__ __launch_bounds__(256) void bucket_csr(const unsigned int* __restrict__ bstore,
                                                  const int* __restrict__ bcnt,
                                                  const int* __restrict__ bbase,
                                                  int* __restrict__ row_ptr,
                                                  int* __restrict__ col, int N) {
    __shared__ int lcnt[256], lexcl[256], lrank[256];
    int b = blockIdx.x, t = threadIdx.x;
    int nb = bcnt[b], base = bbase[b];
    lcnt[t] = 0; lrank[t] = 0;
    __syncthreads();
    for (int i = t; i < nb; i += 256)
        atomicAdd(&lcnt[(bstore[base + i] >> 16) & 255], 1);
    __syncthreads();
    int v = lcnt[t];
    lexcl[t] = v;
    __syncthreads();
    for (int off = 1; off < 256; off <<= 1) {
        int u = (t >= off) ? lexcl[t - off] : 0;
        __syncthreads();
        lexcl[t] += u;
        __syncthreads();
    }
    int ex = lexcl[t] - v;
    __syncthreads();
    lexcl[t] = ex;
    __syncthreads();
    int node = (b << 8) + t;
    if (node < N) row_ptr[node] = base + ex;
    for (int i = t; i < nb; i += 256) {
        unsigned int pk = bstore[base + i];
        int d8 = (pk >> 16) & 255;
        int r = atomicAdd(&lrank[d8], 1);
        col[base + lexcl[d8] + r] = (int)(pk & 0xFFFFu);
    }
}

// ========== GEMM1 (MFMA f16): h1[N,64](f16) = x[N,128] @ W1[128,64] + att1 ==========
// Last block (blockIdx.x == gblocks) instead computes wa = W2@a_src2, wb = W2@a_dst2.
__global__ __launch_bounds__(256) void gemm1_kernel(const float* __restrict__ x,
                                                    const float* __restrict__ W,
                                                    const float* __restrict__ asrc,
                                                    const float* __restrict__ adst,
                                                    _Float16* __restrict__ hout,
                                                    float* __restrict__ av,
                                                    float* __restrict__ bv, int N,
                                                    int gblocks,
                                                    const float* __restrict__ W2,
                                                    const float* __restrict__ as2,
                                                    const float* __restrict__ ad2,
                                                    float* __restrict__ wa,
                                                    float* __restrict__ wb) {
    if (blockIdx.x == (unsigned)gblocks) {
        int k = threadIdx.x;
        if (k < 64) {
            const float* wr = W2 + k * 128;
            float sa = 0.f, sb = 0.f;
#pragma unroll 8
            for (int c = 0; c < 128; ++c) {
                float w = wr[c];
                sa = fmaf(w, as2[c], sa);
                sb = fmaf(w, ad2[c], sb);
            }
            wa[k] = sa; wb[k] = sb;
        }
        return;
    }
    __shared__ unsigned int sWu[4096];  // 16 frags * 64 lanes * 4 uints (16 KB)
    for (int p = threadIdx.x; p < 4096; p += 256) {
        int frag = p >> 8;
        int lane = (p >> 2) & 63;
        int j2   = p & 3;
        int chunk = frag >> 2, nt = frag & 3;
        int k = chunk * 32 + ((lane >> 4) << 3) + (j2 << 1);
        int n = nt * 16 + (lane & 15);
        union { _Float16 h[2]; unsigned int u; } pk;
        pk.h[0] = (_Float16)W[k * 64 + n];
        pk.h[1] = (_Float16)W[(k + 1) * 64 + n];
        sWu[p] = pk.u;
    }
    __syncthreads();

    int lane = threadIdx.x & 63;
    int wid  = threadIdx.x >> 6;
    int rbase = blockIdx.x * 64 + wid * 16;
    int l15 = lane & 15, quad = lane >> 4;
    int rA = rbase + l15; if (rA >= N) rA = N - 1;

    const unsigned int* fragbase = &sWu[lane * 4];
    f32x4 z = {0.f, 0.f, 0.f, 0.f};
    f32x4 acc[4] = {z, z, z, z};

#pragma unroll
    for (int chunk = 0; chunk < 4; ++chunk) {
        const float* xp = x + (size_t)rA * 128 + chunk * 32 + quad * 8;
        float4 f0 = *((const float4*)xp);
        float4 f1 = *((const float4*)(xp + 4));
        f16x8 af;
        af[0] = (_Float16)f0.x; af[1] = (_Float16)f0.y;
        af[2] = (_Float16)f0.z; af[3] = (_Float16)f0.w;
        af[4] = (_Float16)f1.x; af[5] = (_Float16)f1.y;
        af[6] = (_Float16)f1.z; af[7] = (_Float16)f1.w;
#pragma unroll
        for (int t = 0; t < 4; ++t) {
            f16x8 bf = *((const f16x8*)(fragbase + (chunk * 4 + t) * 256));
            acc[t] = __builtin_amdgcn_mfma_f32_16x16x32_f16(af, bf, acc[t], 0, 0, 0);
        }
    }

    float asc[4], adc[4];
#pragma unroll
    for (int t = 0; t < 4; ++t) { asc[t] = asrc[t * 16 + l15]; adc[t] = adst[t * 16 + l15]; }
#pragma unroll
    for (int reg = 0; reg < 4; ++reg) {
        int r = rbase + quad * 4 + reg;
        bool ok = (r < N);
#pragma unroll
        for (int t = 0; t < 4; ++t) {
            float v = acc[t][reg];
            if (ok) hout[(size_t)r * 64 + t * 16 + l15] = (_Float16)v;
            float pa = v * asc[t], pb = v * adc[t];
            pa += __shfl_xor(pa, 1); pb += __shfl_xor(pb, 1);
            pa += __shfl_xor(pa, 2); pb += __shfl_xor(pb, 2);
            pa += __shfl_xor(pa, 4); pb += __shfl_xor(pb, 4);
            if (ok && (lane & 7) == 0) {
                int head = t * 2 + (l15 >> 3);
                av[r * 8 + head] = pa;
                bv[r * 8 + head] = pb;
            }
        }
    }
}

// ========== fused layer-1 softmax-aggregate + layer-2 att coeffs ==========
// 512-thr blocks (8 waves, 8 nodes/block) for full wave-slot occupancy.
// Wave = 1 node; 8 groups of 8 lanes own edges e = beg+g, step 8.
__global__ __launch_bounds__(512) void agg1_kernel(const int* __restrict__ rp,
                                                   const int* __restrict__ col,
                                                   const float* __restrict__ av,
                                                   const float* __restrict__ bv,
                                                   const __half* __restrict__ h1,
                                                   const float* __restrict__ b1,
                                                   const float* __restrict__ wa,
                                                   const float* __restrict__ wb,
                                                   _Float16* __restrict__ out1,
                                                   float* __restrict__ av2,
                                                   float* __restrict__ bv2, int N) {
    int node = blockIdx.x * 8 + (threadIdx.x >> 6);
    int lane = threadIdx.x & 63;
    if (node >= N) return;
    int g = lane >> 3, gl = lane & 7;
    int beg = rp[node], end = rp[node + 1];
    int last = end - 1;
    float bd = bv[node * 8 + gl];
    const uint4* hrow = (const uint4*)h1;     // row stride = 8 uint4 (64 halfs)

    int e  = beg + g;
    uint4 zero4 = {0u, 0u, 0u, 0u};
    int c = col[e <= last ? e : last];
    int e2 = e + 8;
    int cn = col[e2 <= last ? e2 : last];
    float avc = 0.f; uint4 hc = zero4;
    if (e < end) { avc = av[c * 8 + gl]; hc = hrow[(size_t)c * 8 + gl]; }

    float s = 0.f, a0 = 0.f, a1 = 0.f, a2 = 0.f, a3 = 0.f,
          a4 = 0.f, a5 = 0.f, a6 = 0.f, a7 = 0.f;
    for (; e < end; e += 8) {
        int en = e + 8;
        float avn = 0.f; uint4 hn = zero4;
        if (en < end) { avn = av[cn * 8 + gl]; hn = hrow[(size_t)cn * 8 + gl]; }
        int ef = en + 8;
        int cf = col[ef <= last ? ef : last];
        float l = avc + bd;
        l = l > 0.f ? l : NEG_SLOPE * l;
        float w = __expf(l);
        float2 f0 = __half22float2(*(const __half2*)&hc.x);
        float2 f1 = __half22float2(*(const __half2*)&hc.y);
        float2 f2 = __half22float2(*(const __half2*)&hc.z);
        float2 f3 = __half22float2(*(const __half2*)&hc.w);
        s += w;
        a0 = fmaf(w, f0.x, a0); a1 = fmaf(w, f0.y, a1);
        a2 = fmaf(w, f1.x, a2); a3 = fmaf(w, f1.y, a3);
        a4 = fmaf(w, f2.x, a4); a5 = fmaf(w, f2.y, a5);
        a6 = fmaf(w, f3.x, a6); a7 = fmaf(w, f3.y, a7);
        avc = avn; hc = hn; cn = cf;
    }
#pragma unroll
    for (int off = 8; off < 64; off <<= 1) {
        s  += __shfl_xor(s, off);
        a0 += __shfl_xor(a0, off); a1 += __shfl_xor(a1, off);
        a2 += __shfl_xor(a2, off); a3 += __shfl_xor(a3, off);
        a4 += __shfl_xor(a4, off); a5 += __shfl_xor(a5, off);
        a6 += __shfl_xor(a6, off); a7 += __shfl_xor(a7, off);
    }
    // every lane now holds the full totals for channels 8gl..8gl+7
    float inv = 1.0f / s;
    float4 bb0 = ((const float4*)b1)[gl * 2];
    float4 bb1 = ((const float4*)b1)[gl * 2 + 1];
    float v0 = a0 * inv + bb0.x, v1 = a1 * inv + bb0.y;
    float v2 = a2 * inv + bb0.z, v3 = a3 * inv + bb0.w;
    float v4 = a4 * inv + bb1.x, v5 = a5 * inv + bb1.y;
    float v6 = a6 * inv + bb1.z, v7 = a7 * inv + bb1.w;
    v0 = v0 > 0.f ? v0 : expm1f(v0); v1 = v1 > 0.f ? v1 : expm1f(v1);
    v2 = v2 > 0.f ? v2 : expm1f(v2); v3 = v3 > 0.f ? v3 : expm1f(v3);
    v4 = v4 > 0.f ? v4 : expm1f(v4); v5 = v5 > 0.f ? v5 : expm1f(v5);
    v6 = v6 > 0.f ? v6 : expm1f(v6); v7 = v7 > 0.f ? v7 : expm1f(v7);
    // layer-2 attention coefficients (dot with projected vectors)
    float4 wa0 = ((const float4*)wa)[gl * 2], wa1 = ((const float4*)wa)[gl * 2 + 1];
    float4 wb0 = ((const float4*)wb)[gl * 2], wb1 = ((const float4*)wb)[gl * 2 + 1];
    float pa = v0 * wa0.x + v1 * wa0.y + v2 * wa0.z + v3 * wa0.w
             + v4 * wa1.x + v5 * wa1.y + v6 * wa1.z + v7 * wa1.w;
    float pb = v0 * wb0.x + v1 * wb0.y + v2 * wb0.z + v3 * wb0.w
             + v4 * wb1.x + v5 * wb1.y + v6 * wb1.z + v7 * wb1.w;
    pa += __shfl_xor(pa, 1); pb += __shfl_xor(pb, 1);
    pa += __shfl_xor(pa, 2); pb += __shfl_xor(pb, 2);
    pa += __shfl_xor(pa, 4); pb += __shfl_xor(pb, 4);
    if (lane == 0) { av2[node] = pa; bv2[node] = pb; }
    if (g == 0) {
        f16x8 o;
        o[0] = (_Float16)v0; o[1] = (_Float16)v1; o[2] = (_Float16)v2; o[3] = (_Float16)v3;
        o[4] = (_Float16)v4; o[5] = (_Float16)v5; o[6] = (_Float16)v6; o[7] = (_Float16)v7;
        ((f16x8*)out1)[(size_t)node * 8 + gl] = o;
    }
}

// ========== fused layer-2 softmax-aggregate in 64-dim out1 space (512 thr) ==========
__global__ __launch_bounds__(512) void agg2_kernel(const int* __restrict__ rp,
                                                   const int* __restrict__ col,
                                                   const float* __restrict__ av,
                                                   const float* __restrict__ bv,
                                                   const __half* __restrict__ out1,
                                                   float* __restrict__ agg64, int N) {
    int node = blockIdx.x * 8 + (threadIdx.x >> 6);
    int lane = threadIdx.x & 63;
    if (node >= N) return;
    int g = lane >> 3, gl = lane & 7;
    int beg = rp[node], end = rp[node + 1];
    int last = end - 1;
    float bd = bv[node];
    const uint4* hrow = (const uint4*)out1;   // row stride = 8 uint4 (64 halfs)

    int e  = beg + g;
    uint4 zero4 = {0u, 0u, 0u, 0u};
    int c = col[e <= last ? e : last];
    int e2 = e + 8;
    int cn = col[e2 <= last ? e2 : last];
    float avc = 0.f; uint4 hc = zero4;
    if (e < end) { avc = av[c]; hc = hrow[(size_t)c * 8 + gl]; }

    float s = 0.f, a0 = 0.f, a1 = 0.f, a2 = 0.f, a3 = 0.f,
          a4 = 0.f, a5 = 0.f, a6 = 0.f, a7 = 0.f;
    for (; e < end; e += 8) {
        int en = e + 8;
        float avn = 0.f; uint4 hn = zero4;
        if (en < end) { avn = av[cn]; hn = hrow[(size_t)cn * 8 + gl]; }
        int ef = en + 8;
        int cf = col[ef <= last ? ef : last];
        float l = avc + bd;
        l = l > 0.f ? l : NEG_SLOPE * l;
        float w = __expf(l);
        float2 f0 = __half22float2(*(const __half2*)&hc.x);
        float2 f1 = __half22float2(*(const __half2*)&hc.y);
        float2 f2 = __half22float2(*(const __half2*)&hc.z);
        float2 f3 = __half22float2(*(const __half2*)&hc.w);
        s += w;
        a0 = fmaf(w, f0.x, a0); a1 = fmaf(w, f0.y, a1);
        a2 = fmaf(w, f1.x, a2); a3 = fmaf(w, f1.y, a3);
        a4 = fmaf(w, f2.x, a4); a5 = fmaf(w, f2.y, a5);
        a6 = fmaf(w, f3.x, a6); a7 = fmaf(w, f3.y, a7);
        avc = avn; hc = hn; cn = cf;
    }
#pragma unroll
    for (int off = 8; off < 64; off <<= 1) {
        s  += __shfl_xor(s, off);
        a0 += __shfl_xor(a0, off); a1 += __shfl_xor(a1, off);
        a2 += __shfl_xor(a2, off); a3 += __shfl_xor(a3, off);
        a4 += __shfl_xor(a4, off); a5 += __shfl_xor(a5, off);
        a6 += __shfl_xor(a6, off); a7 += __shfl_xor(a7, off);
    }
    if (g == 0) {
        float inv = 1.0f / s;
        ((float4*)agg64)[(size_t)node * 16 + gl * 2] =
            make_float4(a0 * inv, a1 * inv, a2 * inv, a3 * inv);
        ((float4*)agg64)[(size_t)node * 16 + gl * 2 + 1] =
            make_float4(a4 * inv, a5 * inv, a6 * inv, a7 * inv);
    }
}

// ========== GEMM2 (MFMA f16): dout[N,128] = agg64[N,64] @ W2[64,128] + b2 ==========
__global__ __launch_bounds__(256) void gemm2_kernel(const float* __restrict__ he,
                                                    const float* __restrict__ W,
                                                    const float* __restrict__ b2,
                                                    float* __restrict__ dout, int N) {
    __shared__ unsigned int sWu[4096];  // 16 frags (16 KB)
    for (int p = threadIdx.x; p < 4096; p += 256) {
        int frag = p >> 8;
        int lane = (p >> 2) & 63;
        int j2   = p & 3;
        int chunk = frag >> 3, nt = frag & 7;
        int k = chunk * 32 + ((lane >> 4) << 3) + (j2 << 1);
        int n = nt * 16 + (lane & 15);
        union { _Float16 h[2]; unsigned int u; } pk;
        pk.h[0] = (_Float16)W[k * 128 + n];
        pk.h[1] = (_Float16)W[(k + 1) * 128 + n];
        sWu[p] = pk.u;
    }
    __syncthreads();

    int lane = threadIdx.x & 63;
    int wid  = threadIdx.x >> 6;
    int rbase = blockIdx.x * 64 + wid * 16;
    int l15 = lane & 15, quad = lane >> 4;
    int rA = rbase + l15; if (rA >= N) rA = N - 1;

    const unsigned int* fragbase = &sWu[lane * 4];
    f32x4 z = {0.f, 0.f, 0.f, 0.f};
    f32x4 acc[8] = {z, z, z, z, z, z, z, z};

#pragma unroll
    for (int chunk = 0; chunk < 2; ++chunk) {
        const float* xp = he + (size_t)rA * 64 + chunk * 32 + quad * 8;
        float4 f0 = *((const float4*)xp);
        float4 f1 = *((const float4*)(xp + 4));
        f16x8 af;
        af[0] = (_Float16)f0.x; af[1] = (_Float16)f0.y;
        af[2] = (_Float16)f0.z; af[3] = (_Float16)f0.w;
        af[4] = (_Float16)f1.x; af[5] = (_Float16)f1.y;
        af[6] = (_Float16)f1.z; af[7] = (_Float16)f1.w;
#pragma unroll
        for (int t = 0; t < 8; ++t) {
            f16x8 bf = *((const f16x8*)(fragbase + (chunk * 8 + t) * 256));
            acc[t] = __builtin_amdgcn_mfma_f32_16x16x32_f16(af, bf, acc[t], 0, 0, 0);
        }
    }

    float bcol[8];
#pragma unroll
    for (int t = 0; t < 8; ++t) bcol[t] = b2[t * 16 + l15];
#pragma unroll
    for (int reg = 0; reg < 4; ++reg) {
        int r = rbase + quad * 4 + reg;
        if (r < N) {
#pragma unroll
            for (int t = 0; t < 8; ++t)
                dout[(size_t)r * 128 + t * 16 + l15] = acc[t][reg] + bcol[t];
        }
    }
}

extern "C" void kernel_launch(void* const* d_in, const int* in_sizes, int n_in,
                              void* d_out, int out_size, void* d_ws, size_t ws_size,
                              hipStream_t stream) {
    const float* x      = (const float*)d_in[0];
    const int*   ei     = (const int*)  d_in[1];
    const float* W1     = (const float*)d_in[2];
    const float* a_src1 = (const float*)d_in[3];
    const float* a_dst1 = (const float*)d_in[4];
    const float* b1     = (const float*)d_in[5];
    const float* W2     = (const float*)d_in[6];
    const float* a_src2 = (const float*)d_in[7];
    const float* a_dst2 = (const float*)d_in[8];
    const float* b2     = (const float*)d_in[9];
    float* dout = (float*)d_out;

    const int N  = in_sizes[0] / 128;
    const int E  = in_sizes[1] / 2;
    const int ET = E + N;                 // edges + self loops
    const int NBUCK = (N + 255) >> 8;     // 196 for N=50000 (<=256 required)
    const int NBLKA = (ET + 4095) >> 12;  // pass-A/0 blocks

    char* wsb = (char*)d_ws;
    _Float16* h1   = (_Float16*)wsb; wsb += (size_t)N * 64 * 2;
    _Float16* out1 = (_Float16*)wsb; wsb += (size_t)N * 64 * 2;
    float* agg64 = (float*)wsb; wsb += (size_t)N * 64 * 4;
    float* av1  = (float*)wsb; wsb += (size_t)N * 8 * 4;
    float* bv1  = (float*)wsb; wsb += (size_t)N * 8 * 4;
    float* av2  = (float*)wsb; wsb += (size_t)N * 4;
    float* bv2  = (float*)wsb; wsb += (size_t)N * 4;
    float* wa   = (float*)wsb; wsb += 64 * 4;
    float* wb   = (float*)wsb; wsb += 64 * 4;
    int* row_ptr = (int*)wsb; wsb += (size_t)(N + 1) * 4;
    int* col     = (int*)wsb; wsb += (size_t)ET * 4;
    unsigned int* bstore = (unsigned int*)wsb; wsb += (size_t)ET * 4;
    int* bcnt  = (int*)wsb; wsb += 256 * 4;
    int* bbase = (int*)wsb; wsb += 256 * 4;
    int* bcur  = (int*)wsb; wsb += 256 * 4;

    const int B = 256;
    const int gblocks = (N + 63) / 64;

    // ---- CSR build (bucket two-pass) ----
    hipMemsetAsync(bcnt, 0, 256 * 4, stream);
    bucket_count<<<NBLKA, B, 0, stream>>>(ei, E, ET, bcnt);
    bucket_scan<<<1, B, 0, stream>>>(bcnt, bbase, bcur, row_ptr, NBUCK, N, ET);
    bucket_scatter<<<NBLKA, B, 0, stream>>>(ei, E, ET, bcur, bstore, NBUCK);
    bucket_csr<<<NBUCK, B, 0, stream>>>(bstore, bcnt, bbase, row_ptr, col, N);

    // ---- layer 1 (gemm1 + fused att2-projection block) ----
    gemm1_kernel<<<gblocks + 1, B, 0, stream>>>(x, W1, a_src1, a_dst1, h1, av1, bv1, N,
                                                gblocks, W2, a_src2, a_dst2, wa, wb);
    agg1_kernel<<<(N + 7) / 8, 512, 0, stream>>>(row_ptr, col, av1, bv1, (const __half*)h1,
                                                 b1, wa, wb, out1, av2, bv2, N);

    // ---- layer 2 (aggregate in 64-dim, then GEMM) ----
    agg2_kernel<<<(N + 7) / 8, 512, 0, stream>>>(row_ptr, col, av2, bv2,
                                                 (const __half*)out1, agg64, N);
    gemm2_kernel<<<gblocks, B, 0, stream>>>(agg64, W2, b2, dout, N);
}

// Round 13
// 217.403 us; speedup vs baseline: 1.0825x; 1.0076x over previous
//
#include <hip/hip_runtime.h>
#include <hip/hip_fp16.h>
#include <math.h>

#define NEG_SLOPE 0.2f

typedef _Float16 f16x8 __attribute__((ext_vector_type(8)));
typedef float    f32x4 __attribute__((ext_vector_type(4)));

__device__ __forceinline__ void get_edge(const int* __restrict__ ei, int E, int e,
                                         int& s, int& d) {
    if (e < E) { s = ei[e]; d = ei[E + e]; }
    else       { s = e - E; d = e - E; }
}

// ================= CSR build: bucket two-pass, no device-scope random atomics ==========
__global__ __launch_bounds__(256) void bucket_count(const int* __restrict__ ei, int E, int ET,
                                                    int* __restrict__ bcnt) {
    __shared__ int lhist[256];
    int t = threadIdx.x;
    lhist[t] = 0;
    __syncthreads();
    int start = blockIdx.x * 4096;
#pragma unroll
    for (int k = 0; k < 16; ++k) {
        int e = start + t + k * 256;
        if (e < ET) { int s, d; get_edge(ei, E, e, s, d); atomicAdd(&lhist[d >> 8], 1); }
    }
    __syncthreads();
    if (lhist[t] > 0) atomicAdd(&bcnt[t], lhist[t]);
}

__global__ void bucket_scan(const int* __restrict__ bcnt, int* __restrict__ bbase,
                            int* __restrict__ bcur, int* __restrict__ row_ptr,
                            int nbuck, int N, int ET) {
    __shared__ int buf[256];
    int t = threadIdx.x;
    int v = (t < nbuck) ? bcnt[t] : 0;
    buf[t] = v;
    __syncthreads();
    for (int off = 1; off < 256; off <<= 1) {
        int u = (t >= off) ? buf[t - off] : 0;
        __syncthreads();
        buf[t] += u;
        __syncthreads();
    }
    if (t < nbuck) { int ex = buf[t] - v; bbase[t] = ex; bcur[t] = ex; }
    if (t == 0) row_ptr[N] = ET;
}

__global__ __launch_bounds__(256) void bucket_scatter(const int* __restrict__ ei, int E, int ET,
                                                      int* __restrict__ bcur,
                                                      unsigned int* __restrict__ bstore,
                                                      int nbuck) {
    __shared__ int lhist[256], lbase[256], lrank[256], gbase[256];
    __shared__ unsigned int sbuf[4096];
    __shared__ int saddr[4096];
    int t = threadIdx.x;
    int start = blockIdx.x * 4096;
    int cnt = ET - start; if (cnt > 4096) cnt = 4096;
    lhist[t] = 0; lrank[t] = 0;
    __syncthreads();
    int mybuck[16]; unsigned int myval[16];
#pragma unroll
    for (int k = 0; k < 16; ++k) {
        int e = start + t + k * 256;
        mybuck[k] = -1;
        if (e < ET) {
            int s, d; get_edge(ei, E, e, s, d);
            mybuck[k] = d >> 8;
            myval[k] = ((unsigned int)d << 16) | (unsigned int)s;
            atomicAdd(&lhist[mybuck[k]], 1);
        }
    }
    __syncthreads();
    int v = lhist[t];
    lbase[t] = v;
    __syncthreads();
    for (int off = 1; off < 256; off <<= 1) {
        int u = (t >= off) ? lbase[t - off] : 0;
        __syncthreads();
        lbase[t] += u;
        __syncthreads();
    }
    int excl = lbase[t] - v;
    if (t < nbuck && v > 0) gbase[t] = atomicAdd(&bcur[t], v);
    __syncthreads();
    lbase[t] = excl;
    __syncthreads();
#pragma unroll
    for (int k = 0; k < 16; ++k) {
        int b = mybuck[k];
        if (b >= 0) {
            int r = atomicAdd(&lrank[b], 1);
            int idx = lbase[b] + r;
            sbuf[idx] = myval[k];
            saddr[idx] = gbase[b] + r;
        }
    }
    __syncthreads();
    for (int j = t; j < cnt; j += 256)
        bstore[saddr[j]] = sbuf[j];
}

__global__ __launch_bounds__(256) void bucket_csr(const unsigned int* __restrict__ bstore,
                                                  const int* __restrict__ bcnt,
                                                  const int* __restrict__ bbase,
                                                  int* __restrict__ row_ptr,
                                                  int* __restrict__ col, int N) {
    __shared__ int lcnt[256], lexcl[256], lrank[256];
    int b = blockIdx.x, t = threadIdx.x;
    int nb = bcnt[b], base = bbase[b];
    lcnt[t] = 0; lrank[t] = 0;
    __syncthreads();
    for (int i = t; i < nb; i += 256)
        atomicAdd(&lcnt[(bstore[base + i] >> 16) & 255], 1);
    __syncthreads();
    int v = lcnt[t];
    lexcl[t] = v;
    __syncthreads();
    for (int off = 1; off < 256; off <<= 1) {
        int u = (t >= off) ? lexcl[t - off] : 0;
        __syncthreads();
        lexcl[t] += u;
        __syncthreads();
    }
    int ex = lexcl[t] - v;
    __syncthreads();
    lexcl[t] = ex;
    __syncthreads();
    int node = (b << 8) + t;
    if (node < N) row_ptr[node] = base + ex;
    for (int i = t; i < nb; i += 256) {
        unsigned int pk = bstore[base + i];
        int d8 = (pk >> 16) & 255;
        int r = atomicAdd(&lrank[d8], 1);
        col[base + lexcl[d8] + r] = (int)(pk & 0xFFFFu);
    }
}

// ========== GEMM1 (MFMA f16): h1[N,64](f16) = x[N,128] @ W1[128,64] + att1 ==========
// Extra block (blockIdx.x == gblocks): computes wa/wb projections AND zeroes bcnt.
__global__ __launch_bounds__(256) void gemm1_kernel(const float* __restrict__ x,
                                                    const float* __restrict__ W,
                                                    const float* __restrict__ asrc,
                                                    const float* __restrict__ adst,
                                                    _Float16* __restrict__ hout,
                                                    float* __restrict__ av,
                                                    float* __restrict__ bv, int N,
                                                    int gblocks,
                                                    const float* __restrict__ W2,
                                                    const float* __restrict__ as2,
                                                    const float* __restrict__ ad2,
                                                    float* __restrict__ wa,
                                                    float* __restrict__ wb,
                                                    int* __restrict__ bcnt) {
    if (blockIdx.x == (unsigned)gblocks) {
        int k = threadIdx.x;
        bcnt[k] = 0;                      // zero bucket counters (256 ints)
        if (k < 64) {
            const float* wr = W2 + k * 128;
            float sa = 0.f, sb = 0.f;
#pragma unroll 8
            for (int c = 0; c < 128; ++c) {
                float w = wr[c];
                sa = fmaf(w, as2[c], sa);
                sb = fmaf(w, ad2[c], sb);
            }
            wa[k] = sa; wb[k] = sb;
        }
        return;
    }
    __shared__ unsigned int sWu[4096];  // 16 frags * 64 lanes * 4 uints (16 KB)
    for (int p = threadIdx.x; p < 4096; p += 256) {
        int frag = p >> 8;
        int lane = (p >> 2) & 63;
        int j2   = p & 3;
        int chunk = frag >> 2, nt = frag & 3;
        int k = chunk * 32 + ((lane >> 4) << 3) + (j2 << 1);
        int n = nt * 16 + (lane & 15);
        union { _Float16 h[2]; unsigned int u; } pk;
        pk.h[0] = (_Float16)W[k * 64 + n];
        pk.h[1] = (_Float16)W[(k + 1) * 64 + n];
        sWu[p] = pk.u;
    }
    __syncthreads();

    int lane = threadIdx.x & 63;
    int wid  = threadIdx.x >> 6;
    int rbase = blockIdx.x * 64 + wid * 16;
    int l15 = lane & 15, quad = lane >> 4;
    int rA = rbase + l15; if (rA >= N) rA = N - 1;

    const unsigned int* fragbase = &sWu[lane * 4];
    f32x4 z = {0.f, 0.f, 0.f, 0.f};
    f32x4 acc[4] = {z, z, z, z};

#pragma unroll
    for (int chunk = 0; chunk < 4; ++chunk) {
        const float* xp = x + (size_t)rA * 128 + chunk * 32 + quad * 8;
        float4 f0 = *((const float4*)xp);
        float4 f1 = *((const float4*)(xp + 4));
        f16x8 af;
        af[0] = (_Float16)f0.x; af[1] = (_Float16)f0.y;
        af[2] = (_Float16)f0.z; af[3] = (_Float16)f0.w;
        af[4] = (_Float16)f1.x; af[5] = (_Float16)f1.y;
        af[6] = (_Float16)f1.z; af[7] = (_Float16)f1.w;
#pragma unroll
        for (int t = 0; t < 4; ++t) {
            f16x8 bf = *((const f16x8*)(fragbase + (chunk * 4 + t) * 256));
            acc[t] = __builtin_amdgcn_mfma_f32_16x16x32_f16(af, bf, acc[t], 0, 0, 0);
        }
    }

    float asc[4], adc[4];
#pragma unroll
    for (int t = 0; t < 4; ++t) { asc[t] = asrc[t * 16 + l15]; adc[t] = adst[t * 16 + l15]; }
#pragma unroll
    for (int reg = 0; reg < 4; ++reg) {
        int r = rbase + quad * 4 + reg;
        bool ok = (r < N);
#pragma unroll
        for (int t = 0; t < 4; ++t) {
            float v = acc[t][reg];
            if (ok) hout[(size_t)r * 64 + t * 16 + l15] = (_Float16)v;
            float pa = v * asc[t], pb = v * adc[t];
            pa += __shfl_xor(pa, 1); pb += __shfl_xor(pb, 1);
            pa += __shfl_xor(pa, 2); pb += __shfl_xor(pb, 2);
            pa += __shfl_xor(pa, 4); pb += __shfl_xor(pb, 4);
            if (ok && (lane & 7) == 0) {
                int head = t * 2 + (l15 >> 3);
                av[r * 8 + head] = pa;
                bv[r * 8 + head] = pb;
            }
        }
    }
}

// ========== fused layer-1 softmax-aggregate + layer-2 att coeffs ==========
// Wave = 1 node; 8 groups of 8 lanes own edges e = beg+g, step 8.
// Depth-3 pipeline: col 3 iters ahead, row/av data 2 iters ahead.
__global__ __launch_bounds__(512) void agg1_kernel(const int* __restrict__ rp,
                                                   const int* __restrict__ col,
                                                   const float* __restrict__ av,
                                                   const float* __restrict__ bv,
                                                   const __half* __restrict__ h1,
                                                   const float* __restrict__ b1,
                                                   const float* __restrict__ wa,
                                                   const float* __restrict__ wb,
                                                   _Float16* __restrict__ out1,
                                                   float* __restrict__ av2,
                                                   float* __restrict__ bv2, int N) {
    int node = blockIdx.x * 8 + (threadIdx.x >> 6);
    int lane = threadIdx.x & 63;
    if (node >= N) return;
    int g = lane >> 3, gl = lane & 7;
    int beg = rp[node], end = rp[node + 1];
    int last = end - 1;
    float bd = bv[node * 8 + gl];
    const uint4* hrow = (const uint4*)h1;     // row stride = 8 uint4 (64 halfs)

    uint4 z4 = {0u, 0u, 0u, 0u};
    int e = beg + g;
    int c0 = col[e      <= last ? e      : last];
    int c1 = col[e + 8  <= last ? e + 8  : last];
    int c2 = col[e + 16 <= last ? e + 16 : last];
    float av0 = 0.f, av1v = 0.f; uint4 h0 = z4, h1v = z4;
    if (e < end)     { av0  = av[c0 * 8 + gl]; h0  = hrow[(size_t)c0 * 8 + gl]; }
    if (e + 8 < end) { av1v = av[c1 * 8 + gl]; h1v = hrow[(size_t)c1 * 8 + gl]; }

    float s = 0.f, a0 = 0.f, a1 = 0.f, a2 = 0.f, a3 = 0.f,
          a4 = 0.f, a5 = 0.f, a6 = 0.f, a7 = 0.f;
    for (; e < end; e += 8) {
        float av2v = 0.f; uint4 h2 = z4;
        if (e + 16 < end) { av2v = av[c2 * 8 + gl]; h2 = hrow[(size_t)c2 * 8 + gl]; }
        int c3 = col[e + 24 <= last ? e + 24 : last];
        float l = av0 + bd;
        l = l > 0.f ? l : NEG_SLOPE * l;
        float w = __expf(l);
        float2 f0 = __half22float2(*(const __half2*)&h0.x);
        float2 f1 = __half22float2(*(const __half2*)&h0.y);
        float2 f2 = __half22float2(*(const __half2*)&h0.z);
        float2 f3 = __half22float2(*(const __half2*)&h0.w);
        s += w;
        a0 = fmaf(w, f0.x, a0); a1 = fmaf(w, f0.y, a1);
        a2 = fmaf(w, f1.x, a2); a3 = fmaf(w, f1.y, a3);
        a4 = fmaf(w, f2.x, a4); a5 = fmaf(w, f2.y, a5);
        a6 = fmaf(w, f3.x, a6); a7 = fmaf(w, f3.y, a7);
        av0 = av1v; h0 = h1v; av1v = av2v; h1v = h2; c2 = c3;
    }
#pragma unroll
    for (int off = 8; off < 64; off <<= 1) {
        s  += __shfl_xor(s, off);
        a0 += __shfl_xor(a0, off); a1 += __shfl_xor(a1, off);
        a2 += __shfl_xor(a2, off); a3 += __shfl_xor(a3, off);
        a4 += __shfl_xor(a4, off); a5 += __shfl_xor(a5, off);
        a6 += __shfl_xor(a6, off); a7 += __shfl_xor(a7, off);
    }
    // every lane now holds the full totals for channels 8gl..8gl+7
    float inv = 1.0f / s;
    float4 bb0 = ((const float4*)b1)[gl * 2];
    float4 bb1 = ((const float4*)b1)[gl * 2 + 1];
    float v0 = a0 * inv + bb0.x, v1 = a1 * inv + bb0.y;
    float v2 = a2 * inv + bb0.z, v3 = a3 * inv + bb0.w;
    float v4 = a4 * inv + bb1.x, v5 = a5 * inv + bb1.y;
    float v6 = a6 * inv + bb1.z, v7 = a7 * inv + bb1.w;
    v0 = v0 > 0.f ? v0 : expm1f(v0); v1 = v1 > 0.f ? v1 : expm1f(v1);
    v2 = v2 > 0.f ? v2 : expm1f(v2); v3 = v3 > 0.f ? v3 : expm1f(v3);
    v4 = v4 > 0.f ? v4 : expm1f(v4); v5 = v5 > 0.f ? v5 : expm1f(v5);
    v6 = v6 > 0.f ? v6 : expm1f(v6); v7 = v7 > 0.f ? v7 : expm1f(v7);
    // layer-2 attention coefficients (dot with projected vectors)
    float4 wa0 = ((const float4*)wa)[gl * 2], wa1 = ((const float4*)wa)[gl * 2 + 1];
    float4 wb0 = ((const float4*)wb)[gl * 2], wb1 = ((const float4*)wb)[gl * 2 + 1];
    float pa = v0 * wa0.x + v1 * wa0.y + v2 * wa0.z + v3 * wa0.w
             + v4 * wa1.x + v5 * wa1.y + v6 * wa1.z + v7 * wa1.w;
    float pb = v0 * wb0.x + v1 * wb0.y + v2 * wb0.z + v3 * wb0.w
             + v4 * wb1.x + v5 * wb1.y + v6 * wb1.z + v7 * wb1.w;
    pa += __shfl_xor(pa, 1); pb += __shfl_xor(pb, 1);
    pa += __shfl_xor(pa, 2); pb += __shfl_xor(pb, 2);
    pa += __shfl_xor(pa, 4); pb += __shfl_xor(pb, 4);
    if (lane == 0) { av2[node] = pa; bv2[node] = pb; }
    if (g == 0) {
        f16x8 o;
        o[0] = (_Float16)v0; o[1] = (_Float16)v1; o[2] = (_Float16)v2; o[3] = (_Float16)v3;
        o[4] = (_Float16)v4; o[5] = (_Float16)v5; o[6] = (_Float16)v6; o[7] = (_Float16)v7;
        ((f16x8*)out1)[(size_t)node * 8 + gl] = o;
    }
}

// ========== fused layer-2 softmax-aggregate in 64-dim out1 space ==========
// Same 8x8 template, depth-3 pipeline.
__global__ __launch_bounds__(512) void agg2_kernel(const int* __restrict__ rp,
                                                   const int* __restrict__ col,
                                                   const float* __restrict__ av,
                                                   const float* __restrict__ bv,
                                                   const __half* __restrict__ out1,
                                                   float* __restrict__ agg64, int N) {
    int node = blockIdx.x * 8 + (threadIdx.x >> 6);
    int lane = threadIdx.x & 63;
    if (node >= N) return;
    int g = lane >> 3, gl = lane & 7;
    int beg = rp[node], end = rp[node + 1];
    int last = end - 1;
    float bd = bv[node];
    const uint4* hrow = (const uint4*)out1;   // row stride = 8 uint4 (64 halfs)

    uint4 z4 = {0u, 0u, 0u, 0u};
    int e = beg + g;
    int c0 = col[e      <= last ? e      : last];
    int c1 = col[e + 8  <= last ? e + 8  : last];
    int c2 = col[e + 16 <= last ? e + 16 : last];
    float av0 = 0.f, av1v = 0.f; uint4 h0 = z4, h1v = z4;
    if (e < end)     { av0  = av[c0]; h0  = hrow[(size_t)c0 * 8 + gl]; }
    if (e + 8 < end) { av1v = av[c1]; h1v = hrow[(size_t)c1 * 8 + gl]; }

    float s = 0.f, a0 = 0.f, a1 = 0.f, a2 = 0.f, a3 = 0.f,
          a4 = 0.f, a5 = 0.f, a6 = 0.f, a7 = 0.f;
    for (; e < end; e += 8) {
        float av2v = 0.f; uint4 h2 = z4;
        if (e + 16 < end) { av2v = av[c2]; h2 = hrow[(size_t)c2 * 8 + gl]; }
        int c3 = col[e + 24 <= last ? e + 24 : last];
        float l = av0 + bd;
        l = l > 0.f ? l : NEG_SLOPE * l;
        float w = __expf(l);
        float2 f0 = __half22float2(*(const __half2*)&h0.x);
        float2 f1 = __half22float2(*(const __half2*)&h0.y);
        float2 f2 = __half22float2(*(const __half2*)&h0.z);
        float2 f3 = __half22float2(*(const __half2*)&h0.w);
        s += w;
        a0 = fmaf(w, f0.x, a0); a1 = fmaf(w, f0.y, a1);
        a2 = fmaf(w, f1.x, a2); a3 = fmaf(w, f1.y, a3);
        a4 = fmaf(w, f2.x, a4); a5 = fmaf(w, f2.y, a5);
        a6 = fmaf(w, f3.x, a6); a7 = fmaf(w, f3.y, a7);
        av0 = av1v; h0 = h1v; av1v = av2v; h1v = h2; c2 = c3;
    }
#pragma unroll
    for (int off = 8; off < 64; off <<= 1) {
        s  += __shfl_xor(s, off);
        a0 += __shfl_xor(a0, off); a1 += __shfl_xor(a1, off);
        a2 += __shfl_xor(a2, off); a3 += __shfl_xor(a3, off);
        a4 += __shfl_xor(a4, off); a5 += __shfl_xor(a5, off);
        a6 += __shfl_xor(a6, off); a7 += __shfl_xor(a7, off);
    }
    if (g == 0) {
        float inv = 1.0f / s;
        ((float4*)agg64)[(size_t)node * 16 + gl * 2] =
            make_float4(a0 * inv, a1 * inv, a2 * inv, a3 * inv);
        ((float4*)agg64)[(size_t)node * 16 + gl * 2 + 1] =
            make_float4(a4 * inv, a5 * inv, a6 * inv, a7 * inv);
    }
}

// ========== GEMM2 (MFMA f16): dout[N,128] = agg64[N,64] @ W2[64,128] + b2 ==========
__global__ __launch_bounds__(256) void gemm2_kernel(const float* __restrict__ he,
                                                    const float* __restrict__ W,
                                                    const float* __restrict__ b2,
                                                    float* __restrict__ dout, int N) {
    __shared__ unsigned int sWu[4096];  // 16 frags (16 KB)
    for (int p = threadIdx.x; p < 4096; p += 256) {
        int frag = p >> 8;
        int lane = (p >> 2) & 63;
        int j2   = p & 3;
        int chunk = frag >> 3, nt = frag & 7;
        int k = chunk * 32 + ((lane >> 4) << 3) + (j2 << 1);
        int n = nt * 16 + (lane & 15);
        union { _Float16 h[2]; unsigned int u; } pk;
        pk.h[0] = (_Float16)W[k * 128 + n];
        pk.h[1] = (_Float16)W[(k + 1) * 128 + n];
        sWu[p] = pk.u;
    }
    __syncthreads();

    int lane = threadIdx.x & 63;
    int wid  = threadIdx.x >> 6;
    int rbase = blockIdx.x * 64 + wid * 16;
    int l15 = lane & 15, quad = lane >> 4;
    int rA = rbase + l15; if (rA >= N) rA = N - 1;

    const unsigned int* fragbase = &sWu[lane * 4];
    f32x4 z = {0.f, 0.f, 0.f, 0.f};
    f32x4 acc[8] = {z, z, z, z, z, z, z, z};

#pragma unroll
    for (int chunk = 0; chunk < 2; ++chunk) {
        const float* xp = he + (size_t)rA * 64 + chunk * 32 + quad * 8;
        float4 f0 = *((const float4*)xp);
        float4 f1 = *((const float4*)(xp + 4));
        f16x8 af;
        af[0] = (_Float16)f0.x; af[1] = (_Float16)f0.y;
        af[2] = (_Float16)f0.z; af[3] = (_Float16)f0.w;
        af[4] = (_Float16)f1.x; af[5] = (_Float16)f1.y;
        af[6] = (_Float16)f1.z; af[7] = (_Float16)f1.w;
#pragma unroll
        for (int t = 0; t < 8; ++t) {
            f16x8 bf = *((const f16x8*)(fragbase + (chunk * 8 + t) * 256));
            acc[t] = __builtin_amdgcn_mfma_f32_16x16x32_f16(af, bf, acc[t], 0, 0, 0);
        }
    }

    float bcol[8];
#pragma unroll
    for (int t = 0; t < 8; ++t) bcol[t] = b2[t * 16 + l15];
#pragma unroll
    for (int reg = 0; reg < 4; ++reg) {
        int r = rbase + quad * 4 + reg;
        if (r < N) {
#pragma unroll
            for (int t = 0; t < 8; ++t)
                dout[(size_t)r * 128 + t * 16 + l15] = acc[t][reg] + bcol[t];
        }
    }
}

extern "C" void kernel_launch(void* const* d_in, const int* in_sizes, int n_in,
                              void* d_out, int out_size, void* d_ws, size_t ws_size,
                              hipStream_t stream) {
    const float* x      = (const float*)d_in[0];
    const int*   ei     = (const int*)  d_in[1];
    const float* W1     = (const float*)d_in[2];
    const float* a_src1 = (const float*)d_in[3];
    const float* a_dst1 = (const float*)d_in[4];
    const float* b1     = (const float*)d_in[5];
    const float* W2     = (const float*)d_in[6];
    const float* a_src2 = (const float*)d_in[7];
    const float* a_dst2 = (const float*)d_in[8];
    const float* b2     = (const float*)d_in[9];
    float* dout = (float*)d_out;

    const int N  = in_sizes[0] / 128;
    const int E  = in_sizes[1] / 2;
    const int ET = E + N;                 // edges + self loops
    const int NBUCK = (N + 255) >> 8;     // 196 for N=50000 (<=256 required)
    const int NBLKA = (ET + 4095) >> 12;  // pass-A/0 blocks

    char* wsb = (char*)d_ws;
    _Float16* h1   = (_Float16*)wsb; wsb += (size_t)N * 64 * 2;
    _Float16* out1 = (_Float16*)wsb; wsb += (size_t)N * 64 * 2;
    float* agg64 = (float*)wsb; wsb += (size_t)N * 64 * 4;
    float* av1  = (float*)wsb; wsb += (size_t)N * 8 * 4;
    float* bv1  = (float*)wsb; wsb += (size_t)N * 8 * 4;
    float* av2  = (float*)wsb; wsb += (size_t)N * 4;
    float* bv2  = (float*)wsb; wsb += (size_t)N * 4;
    float* wa   = (float*)wsb; wsb += 64 * 4;
    float* wb   = (float*)wsb; wsb += 64 * 4;
    int* row_ptr = (int*)wsb; wsb += (size_t)(N + 1) * 4;
    int* col     = (int*)wsb; wsb += (size_t)ET * 4;
    unsigned int* bstore = (unsigned int*)wsb; wsb += (size_t)ET * 4;
    int* bcnt  = (int*)wsb; wsb += 256 * 4;
    int* bbase = (int*)wsb; wsb += 256 * 4;
    int* bcur  = (int*)wsb; wsb += 256 * 4;

    const int B = 256;
    const int gblocks = (N + 63) / 64;

    // ---- gemm1 first (independent of CSR); extra block zeroes bcnt + projects att2 ----
    gemm1_kernel<<<gblocks + 1, B, 0, stream>>>(x, W1, a_src1, a_dst1, h1, av1, bv1, N,
                                                gblocks, W2, a_src2, a_dst2, wa, wb, bcnt);

    // ---- CSR build (bucket two-pass) ----
    bucket_count<<<NBLKA, B, 0, stream>>>(ei, E, ET, bcnt);
    bucket_scan<<<1, B, 0, stream>>>(bcnt, bbase, bcur, row_ptr, NBUCK, N, ET);
    bucket_scatter<<<NBLKA, B, 0, stream>>>(ei, E, ET, bcur, bstore, NBUCK);
    bucket_csr<<<NBUCK, B, 0, stream>>>(bstore, bcnt, bbase, row_ptr, col, N);

    // ---- layer 1 aggregate ----
    agg1_kernel<<<(N + 7) / 8, 512, 0, stream>>>(row_ptr, col, av1, bv1, (const __half*)h1,
                                                 b1, wa, wb, out1, av2, bv2, N);

    // ---- layer 2 (aggregate in 64-dim, then GEMM) ----
    agg2_kernel<<<(N + 7) / 8, 512, 0, stream>>>(row_ptr, col, av2, bv2,
                                                 (const __half*)out1, agg64, N);
    gemm2_kernel<<<gblocks, B, 0, stream>>>(agg64, W2, b2, dout, N);
}